// Round 1
// baseline (814.905 us; speedup 1.0000x reference)
//
#include <hip/hip_runtime.h>
#include <math.h>

// ---------------- constants for this problem ----------------
#define F_IN 182
#define H1   128
#define H2   64

// ---------------- graph preprocessing ----------------
__global__ __launch_bounds__(256) void deg_count(const int* __restrict__ dst,
                                                 int* __restrict__ cnt, int E) {
    int e = blockIdx.x * 256 + threadIdx.x;
    if (e < E) atomicAdd(&cnt[dst[e]], 1);
}

// per-block exclusive scan over 2048 elements (256 threads x 8)
__global__ __launch_bounds__(256) void scan_block(const int* __restrict__ in,
                                                  int* __restrict__ out,
                                                  int* __restrict__ bsums, int Nn) {
    __shared__ int s[256];
    int b = blockIdx.x, t = threadIdx.x;
    int base = b * 2048 + t * 8;
    int v[8]; int sum = 0;
#pragma unroll
    for (int i = 0; i < 8; ++i) { int idx = base + i; v[i] = (idx < Nn) ? in[idx] : 0; sum += v[i]; }
    s[t] = sum; __syncthreads();
    for (int off = 1; off < 256; off <<= 1) {
        int x = (t >= off) ? s[t - off] : 0; __syncthreads();
        s[t] += x; __syncthreads();
    }
    int excl = s[t] - sum;
    if (t == 255) bsums[b] = s[255];
    int run = excl;
#pragma unroll
    for (int i = 0; i < 8; ++i) { int idx = base + i; if (idx < Nn) out[idx] = run; run += v[i]; }
}

__global__ void scan_bsums(int* bs, int nb) {
    if (blockIdx.x == 0 && threadIdx.x == 0) {
        int run = 0;
        for (int i = 0; i < nb; ++i) { int x = bs[i]; bs[i] = run; run += x; }
    }
}

__global__ __launch_bounds__(256) void scan_add(int* __restrict__ offs,
                                                int* __restrict__ cursor,
                                                const int* __restrict__ bs, int Nn) {
    int i = blockIdx.x * 256 + threadIdx.x;
    if (i < Nn) { int o = offs[i] + bs[i >> 11]; offs[i] = o; cursor[i] = o; }
}

__global__ __launch_bounds__(256) void csr_build(const int* __restrict__ src,
                                                 const int* __restrict__ dst,
                                                 int* __restrict__ cursor,
                                                 int* __restrict__ csr, int E) {
    int e = blockIdx.x * 256 + threadIdx.x;
    if (e < E) {
        int p = atomicAdd(&cursor[dst[e]], 1);
        csr[p] = src[e];
    }
}

// ---------------- mean aggregation (gather over CSR) ----------------
// one 32-lane group per node; F/32 floats per lane
template <int F>
__global__ __launch_bounds__(256) void agg_mean(const int* __restrict__ offs,
                                                const int* __restrict__ degs,
                                                const int* __restrict__ csr,
                                                const float* __restrict__ Y,
                                                float* __restrict__ out, int Nn) {
    int gid = blockIdx.x * 8 + (threadIdx.x >> 5);
    int l = threadIdx.x & 31;
    if (gid >= Nn) return;
    int start = offs[gid];
    int deg = degs[gid];
    if (F == 128) {
        float4 acc = make_float4(0.f, 0.f, 0.f, 0.f);
        for (int t = 0; t < deg; ++t) {
            int s = csr[start + t];
            float4 r = *(const float4*)(Y + (size_t)s * F + l * 4);
            acc.x += r.x; acc.y += r.y; acc.z += r.z; acc.w += r.w;
        }
        float inv = 1.f / fmaxf((float)deg, 1.f);
        acc.x *= inv; acc.y *= inv; acc.z *= inv; acc.w *= inv;
        *(float4*)(out + (size_t)gid * F + l * 4) = acc;
    } else {
        float2 acc = make_float2(0.f, 0.f);
        for (int t = 0; t < deg; ++t) {
            int s = csr[start + t];
            float2 r = *(const float2*)(Y + (size_t)s * F + l * 2);
            acc.x += r.x; acc.y += r.y;
        }
        float inv = 1.f / fmaxf((float)deg, 1.f);
        acc.x *= inv; acc.y *= inv;
        *(float2*)(out + (size_t)gid * F + l * 2) = acc;
    }
}

// ---------------- fp32 tiled GEMM: out = A @ W^T (+ bias + aggmean, relu) ----------------
// A: [M,K] row-major, W: [BN,K] row-major, out: [M,BN]
template <int BN, bool EPI, bool RELU>
__global__ __launch_bounds__(256) void gemm_nt(const float* __restrict__ A,
                                               const float* __restrict__ W,
                                               const float* __restrict__ bias,
                                               const float* __restrict__ aggmean,
                                               float* __restrict__ out,
                                               int M, int K) {
    constexpr int BM = 64, BK = 32;
    constexpr int NJ = BN / 32;
    __shared__ float xs[BM][BK + 1];
    __shared__ float ws[BN][BK + 1];
    int tid = threadIdx.x;
    int tx = tid & 31, ty = tid >> 5;
    int row0 = blockIdx.x * BM;
    float acc[8][NJ] = {};
    for (int k0 = 0; k0 < K; k0 += BK) {
        for (int idx = tid; idx < BM * BK; idx += 256) {
            int r = idx >> 5, k = idx & 31;
            int gr = row0 + r, gk = k0 + k;
            xs[r][k] = (gr < M && gk < K) ? A[(size_t)gr * K + gk] : 0.f;
        }
        for (int idx = tid; idx < BN * BK; idx += 256) {
            int c = idx >> 5, k = idx & 31;
            int gk = k0 + k;
            ws[c][k] = (gk < K) ? W[(size_t)c * K + gk] : 0.f;
        }
        __syncthreads();
#pragma unroll
        for (int k = 0; k < BK; ++k) {
            float wv[NJ];
#pragma unroll
            for (int j = 0; j < NJ; ++j) wv[j] = ws[tx + 32 * j][k];
#pragma unroll
            for (int i = 0; i < 8; ++i) {
                float xv = xs[ty + 8 * i][k];
#pragma unroll
                for (int j = 0; j < NJ; ++j) acc[i][j] += xv * wv[j];
            }
        }
        __syncthreads();
    }
#pragma unroll
    for (int i = 0; i < 8; ++i) {
        int gr = row0 + ty + 8 * i;
        if (gr < M) {
#pragma unroll
            for (int j = 0; j < NJ; ++j) {
                int c = tx + 32 * j;
                float v = acc[i][j];
                if (EPI) {
                    v += bias[c];
                    v += aggmean[(size_t)gr * BN + c];
                }
                if (RELU) v = fmaxf(v, 0.f);
                out[(size_t)gr * BN + c] = v;
            }
        }
    }
}

// ---------------- classifier head + log_softmax (C=2) ----------------
__global__ __launch_bounds__(256) void head_lsm(const float* __restrict__ h2,
                                                const float* __restrict__ Wl,
                                                const float* __restrict__ bl,
                                                float* __restrict__ out, int Nn) {
    __shared__ float w[2][64];
    __shared__ float b[2];
    int tid = threadIdx.x;
    if (tid < 128) w[tid >> 6][tid & 63] = Wl[tid];
    if (tid < 2) b[tid] = bl[tid];
    __syncthreads();
    int n = blockIdx.x * 256 + tid;
    if (n >= Nn) return;
    const float4* row = (const float4*)(h2 + (size_t)n * 64);
    float a0 = 0.f, a1 = 0.f;
#pragma unroll
    for (int m = 0; m < 16; ++m) {
        float4 h = row[m];
        a0 += h.x * w[0][4 * m] + h.y * w[0][4 * m + 1] + h.z * w[0][4 * m + 2] + h.w * w[0][4 * m + 3];
        a1 += h.x * w[1][4 * m] + h.y * w[1][4 * m + 1] + h.z * w[1][4 * m + 2] + h.w * w[1][4 * m + 3];
    }
    a0 += b[0]; a1 += b[1];
    float mx = fmaxf(a0, a1);
    float lse = mx + logf(expf(a0 - mx) + expf(a1 - mx));
    float2 r; r.x = a0 - lse; r.y = a1 - lse;
    ((float2*)out)[n] = r;
}

extern "C" void kernel_launch(void* const* d_in, const int* in_sizes, int n_in,
                              void* d_out, int out_size, void* d_ws, size_t ws_size,
                              hipStream_t stream) {
    const float* x    = (const float*)d_in[0];
    const int*   ei   = (const int*)d_in[1];
    const float* W1l  = (const float*)d_in[2];
    const float* W1r  = (const float*)d_in[3];
    const float* b1   = (const float*)d_in[4];
    const float* W2l  = (const float*)d_in[5];
    const float* W2r  = (const float*)d_in[6];
    const float* b2   = (const float*)d_in[7];
    const float* Wlin = (const float*)d_in[8];
    const float* blin = (const float*)d_in[9];
    float* outp = (float*)d_out;

    const int N = in_sizes[0] / F_IN;
    const int E = in_sizes[1] / 2;
    const int* srcv = ei;
    const int* dstv = ei + E;

    // workspace layout
    char* ws = (char*)d_ws;
    size_t o = 0;
    auto alloc = [&](size_t bytes) { size_t r = o; o += (bytes + 255) & ~(size_t)255; return r; };
    int* cnt_i  = (int*)(ws + alloc((size_t)N * 4));
    int* offs   = (int*)(ws + alloc((size_t)N * 4));
    int* cursor = (int*)(ws + alloc((size_t)N * 4));
    int* bsums  = (int*)(ws + alloc(1024));
    int* csr    = (int*)(ws + alloc((size_t)E * 4));
    float* y1l  = (float*)(ws + alloc((size_t)N * H1 * 4));
    float* agg1 = (float*)(ws + alloc((size_t)N * H1 * 4));
    float* h1   = (float*)(ws + alloc((size_t)N * H1 * 4));
    float* y2l  = y1l;                      // reuse (y1l dead after agg_mean<128>)
    float* agg2 = agg1;                     // reuse (agg1 dead after G2)
    float* h2   = y1l + (size_t)N * H2;     // second half of y1l region

    const int eb = (E + 255) / 256;
    const int nb = (N + 2047) / 2048;
    const int nthr = (N + 255) / 256;
    const int gblk = (N + 63) / 64;
    const int ablk = (N + 7) / 8;

    // 1. degree count
    hipMemsetAsync(cnt_i, 0, (size_t)N * 4, stream);
    deg_count<<<eb, 256, 0, stream>>>(dstv, cnt_i, E);
    // 2. exclusive scan -> offsets, cursor
    scan_block<<<nb, 256, 0, stream>>>(cnt_i, offs, bsums, N);
    scan_bsums<<<1, 64, 0, stream>>>(bsums, nb);
    scan_add<<<nthr, 256, 0, stream>>>(offs, cursor, bsums, N);
    // 3. CSR fill
    csr_build<<<eb, 256, 0, stream>>>(srcv, dstv, cursor, csr, E);

    // ---- layer 1 ----
    gemm_nt<H1, false, false><<<gblk, 256, 0, stream>>>(x, W1l, nullptr, nullptr, y1l, N, F_IN);
    agg_mean<H1><<<ablk, 256, 0, stream>>>(offs, cnt_i, csr, y1l, agg1, N);
    gemm_nt<H1, true, true><<<gblk, 256, 0, stream>>>(x, W1r, b1, agg1, h1, N, F_IN);

    // ---- layer 2 ----
    gemm_nt<H2, false, false><<<gblk, 256, 0, stream>>>(h1, W2l, nullptr, nullptr, y2l, N, H1);
    agg_mean<H2><<<ablk, 256, 0, stream>>>(offs, cnt_i, csr, y2l, agg2, N);
    gemm_nt<H2, true, true><<<gblk, 256, 0, stream>>>(h1, W2r, b2, agg2, h2, N, H1);

    // ---- head ----
    head_lsm<<<nthr, 256, 0, stream>>>(h2, Wlin, blin, outp, N);
}

// Round 2
// 308.885 us; speedup vs baseline: 2.6382x; 2.6382x over previous
//
#include <hip/hip_runtime.h>
#include <math.h>

#define F_IN 182
#define KP1  192   // padded K for layer 1
#define H1   128
#define H2   64

typedef short bf16x8 __attribute__((ext_vector_type(8)));
typedef float f32x4 __attribute__((ext_vector_type(4)));

__device__ __forceinline__ float b2f(short s) {
    unsigned u = ((unsigned)(unsigned short)s) << 16;
    return __builtin_bit_cast(float, u);
}
__device__ __forceinline__ short f2b(float f) {
    unsigned u = __builtin_bit_cast(unsigned, f);
    unsigned r = (u + 0x7FFFu + ((u >> 16) & 1u)) >> 16;
    return (short)(unsigned short)r;
}

// ---------------- graph preprocessing ----------------
__global__ __launch_bounds__(256) void deg_count(const int* __restrict__ dst,
                                                 int* __restrict__ cnt, int E) {
    int e = blockIdx.x * 256 + threadIdx.x;
    if (e < E) atomicAdd(&cnt[dst[e]], 1);
}

__global__ __launch_bounds__(256) void scan_block(const int* __restrict__ in,
                                                  int* __restrict__ out,
                                                  int* __restrict__ bsums, int Nn) {
    __shared__ int s[256];
    int b = blockIdx.x, t = threadIdx.x;
    int base = b * 2048 + t * 8;
    int v[8]; int sum = 0;
#pragma unroll
    for (int i = 0; i < 8; ++i) { int idx = base + i; v[i] = (idx < Nn) ? in[idx] : 0; sum += v[i]; }
    s[t] = sum; __syncthreads();
    for (int off = 1; off < 256; off <<= 1) {
        int x = (t >= off) ? s[t - off] : 0; __syncthreads();
        s[t] += x; __syncthreads();
    }
    int excl = s[t] - sum;
    if (t == 255) bsums[b] = s[255];
    int run = excl;
#pragma unroll
    for (int i = 0; i < 8; ++i) { int idx = base + i; if (idx < Nn) out[idx] = run; run += v[i]; }
}

__global__ void scan_bsums(int* bs, int nb) {
    if (blockIdx.x == 0 && threadIdx.x == 0) {
        int run = 0;
        for (int i = 0; i < nb; ++i) { int x = bs[i]; bs[i] = run; run += x; }
    }
}

__global__ __launch_bounds__(256) void scan_add(int* __restrict__ offs,
                                                int* __restrict__ cursor,
                                                const int* __restrict__ bs, int Nn) {
    int i = blockIdx.x * 256 + threadIdx.x;
    if (i < Nn) { int o = offs[i] + bs[i >> 11]; offs[i] = o; cursor[i] = o; }
}

__global__ __launch_bounds__(256) void csr_build(const int* __restrict__ src,
                                                 const int* __restrict__ dst,
                                                 int* __restrict__ cursor,
                                                 int* __restrict__ csr, int E) {
    int e = blockIdx.x * 256 + threadIdx.x;
    if (e < E) {
        int p = atomicAdd(&cursor[dst[e]], 1);
        csr[p] = src[e];
    }
}

// ---------------- conversions ----------------
__global__ __launch_bounds__(256) void conv_x(const float* __restrict__ x,
                                              short* __restrict__ xb, int Nn) {
    int row = blockIdx.x * 4 + (threadIdx.x >> 6);
    int l = threadIdx.x & 63;
    if (row >= Nn) return;
    const float* xr = x + (size_t)row * F_IN;
    short* o = xb + (size_t)row * KP1;
#pragma unroll
    for (int i = 0; i < 3; ++i) {
        int c = l + i * 64;
        float v = (c < F_IN) ? xr[c] : 0.f;
        o[c] = f2b(v);
    }
}

__global__ __launch_bounds__(256) void conv_w1(const float* __restrict__ Wl,
                                               const float* __restrict__ Wr,
                                               short* __restrict__ o) {
    int idx = blockIdx.x * 256 + threadIdx.x;
    if (idx >= 256 * KP1) return;
    int r = idx / KP1, k = idx - r * KP1;
    float v = 0.f;
    if (k < F_IN) v = (r < 128) ? Wl[r * F_IN + k] : Wr[(r - 128) * F_IN + k];
    o[idx] = f2b(v);
}

__global__ __launch_bounds__(256) void conv_w2(const float* __restrict__ Wl,
                                               const float* __restrict__ Wr,
                                               short* __restrict__ o) {
    int idx = blockIdx.x * 256 + threadIdx.x;
    if (idx >= 128 * 128) return;
    int r = idx >> 7, k = idx & 127;
    float v = (r < 64) ? Wl[r * 128 + k] : Wr[(r - 64) * 128 + k];
    o[idx] = f2b(v);
}

// ---------------- bf16 MFMA GEMM: y = A @ W^T, split output halves ----------------
// A: [M][KK] bf16, W: [NC][KK] bf16 row-major. outL/outR: [M][NC/2] bf16 each.
template <int NC, int KK>
__global__ __launch_bounds__(256) void gemm_mfma(const short* __restrict__ A,
                                                 const short* __restrict__ W,
                                                 short* __restrict__ outL,
                                                 short* __restrict__ outR, int M) {
    constexpr int BM = 64, BK = 64;
    constexpr int LDA = BK + 8;        // 72 shorts = 144 B rows -> 2-way bank aliasing (free)
    constexpr int WN = NC / 4;         // cols per wave
    constexpr int NJ = WN / 16;        // 16-col frags per wave
    __shared__ __attribute__((aligned(16))) short sA[BM][LDA];
    __shared__ __attribute__((aligned(16))) short sB[NC][LDA];
    int tid = threadIdx.x;
    int wid = tid >> 6, lane = tid & 63;
    int row0 = blockIdx.x * BM;
    f32x4 acc[4][NJ] = {};
    for (int k0 = 0; k0 < KK; k0 += BK) {
        // stage A: 64x64 bf16 via 16B chunks
        for (int c = tid; c < BM * (BK / 8); c += 256) {
            int r = c >> 3, kc = (c & 7) * 8;
            int gr = row0 + r;
            bf16x8 v = {};
            if (gr < M) v = *(const bf16x8*)(A + (size_t)gr * KK + k0 + kc);
            *(bf16x8*)(&sA[r][kc]) = v;
        }
        // stage B: NC x 64
        for (int c = tid; c < NC * (BK / 8); c += 256) {
            int r = c >> 3, kc = (c & 7) * 8;
            *(bf16x8*)(&sB[r][kc]) = *(const bf16x8*)(W + (size_t)r * KK + k0 + kc);
        }
        __syncthreads();
#pragma unroll
        for (int ks = 0; ks < 2; ++ks) {
            int kb = ks * 32 + (lane >> 4) * 8;
            bf16x8 af[4];
#pragma unroll
            for (int mi = 0; mi < 4; ++mi)
                af[mi] = *(const bf16x8*)(&sA[mi * 16 + (lane & 15)][kb]);
#pragma unroll
            for (int ni = 0; ni < NJ; ++ni) {
                bf16x8 bfr = *(const bf16x8*)(&sB[wid * WN + ni * 16 + (lane & 15)][kb]);
#pragma unroll
                for (int mi = 0; mi < 4; ++mi)
                    acc[mi][ni] = __builtin_amdgcn_mfma_f32_16x16x32_bf16(af[mi], bfr, acc[mi][ni], 0, 0, 0);
            }
        }
        __syncthreads();
    }
    constexpr int HN = NC / 2;
#pragma unroll
    for (int mi = 0; mi < 4; ++mi) {
#pragma unroll
        for (int ni = 0; ni < NJ; ++ni) {
            int gc = wid * WN + ni * 16 + (lane & 15);
#pragma unroll
            for (int r = 0; r < 4; ++r) {
                int gr = row0 + mi * 16 + (lane >> 4) * 4 + r;
                if (gr < M) {
                    short v = f2b(acc[mi][ni][r]);
                    if (gc < HN) outL[(size_t)gr * HN + gc] = v;
                    else         outR[(size_t)gr * HN + gc - HN] = v;
                }
            }
        }
    }
}

// ---------------- fused mean-aggregate + residual-linear + bias + relu ----------------
template <int F>
__global__ __launch_bounds__(256) void agg_fuse(const int* __restrict__ offs,
                                                const int* __restrict__ degs,
                                                const int* __restrict__ csr,
                                                const short* __restrict__ yl,
                                                const short* __restrict__ yr,
                                                const float* __restrict__ bias,
                                                short* __restrict__ h, int Nn) {
    int gid = blockIdx.x * 8 + (threadIdx.x >> 5);
    int l = threadIdx.x & 31;
    if (gid >= Nn) return;
    int start = offs[gid], deg = degs[gid];
    if (F == 128) {
        float a0 = 0.f, a1 = 0.f, a2 = 0.f, a3 = 0.f;
        for (int t = 0; t < deg; ++t) {
            int s = csr[start + t];
            short4 v = *(const short4*)(yl + (size_t)s * F + l * 4);
            a0 += b2f(v.x); a1 += b2f(v.y); a2 += b2f(v.z); a3 += b2f(v.w);
        }
        float inv = 1.f / fmaxf((float)deg, 1.f);
        short4 rv = *(const short4*)(yr + (size_t)gid * F + l * 4);
        short4 o;
        o.x = f2b(fmaxf(a0 * inv + b2f(rv.x) + bias[l * 4 + 0], 0.f));
        o.y = f2b(fmaxf(a1 * inv + b2f(rv.y) + bias[l * 4 + 1], 0.f));
        o.z = f2b(fmaxf(a2 * inv + b2f(rv.z) + bias[l * 4 + 2], 0.f));
        o.w = f2b(fmaxf(a3 * inv + b2f(rv.w) + bias[l * 4 + 3], 0.f));
        *(short4*)(h + (size_t)gid * F + l * 4) = o;
    } else {
        float a0 = 0.f, a1 = 0.f;
        for (int t = 0; t < deg; ++t) {
            int s = csr[start + t];
            short2 v = *(const short2*)(yl + (size_t)s * F + l * 2);
            a0 += b2f(v.x); a1 += b2f(v.y);
        }
        float inv = 1.f / fmaxf((float)deg, 1.f);
        short2 rv = *(const short2*)(yr + (size_t)gid * F + l * 2);
        short2 o;
        o.x = f2b(fmaxf(a0 * inv + b2f(rv.x) + bias[l * 2 + 0], 0.f));
        o.y = f2b(fmaxf(a1 * inv + b2f(rv.y) + bias[l * 2 + 1], 0.f));
        *(short2*)(h + (size_t)gid * F + l * 2) = o;
    }
}

// ---------------- head: h2 @ Wlin^T + b, log_softmax (C=2) ----------------
__global__ __launch_bounds__(256) void head_lsm(const short* __restrict__ h2,
                                                const float* __restrict__ Wl,
                                                const float* __restrict__ bl,
                                                float* __restrict__ out, int Nn) {
    int gid = blockIdx.x * 8 + (threadIdx.x >> 5);
    int l = threadIdx.x & 31;
    if (gid >= Nn) return;
    short2 v = *(const short2*)(h2 + (size_t)gid * 64 + l * 2);
    float h0 = b2f(v.x), h1v = b2f(v.y);
    float a0 = h0 * Wl[2 * l] + h1v * Wl[2 * l + 1];
    float a1 = h0 * Wl[64 + 2 * l] + h1v * Wl[64 + 2 * l + 1];
#pragma unroll
    for (int m = 16; m >= 1; m >>= 1) {
        a0 += __shfl_xor(a0, m, 32);
        a1 += __shfl_xor(a1, m, 32);
    }
    if (l == 0) {
        a0 += bl[0]; a1 += bl[1];
        float mx = fmaxf(a0, a1);
        float lse = mx + logf(expf(a0 - mx) + expf(a1 - mx));
        out[2 * gid] = a0 - lse;
        out[2 * gid + 1] = a1 - lse;
    }
}

extern "C" void kernel_launch(void* const* d_in, const int* in_sizes, int n_in,
                              void* d_out, int out_size, void* d_ws, size_t ws_size,
                              hipStream_t stream) {
    const float* x    = (const float*)d_in[0];
    const int*   ei   = (const int*)d_in[1];
    const float* W1l  = (const float*)d_in[2];
    const float* W1r  = (const float*)d_in[3];
    const float* b1   = (const float*)d_in[4];
    const float* W2l  = (const float*)d_in[5];
    const float* W2r  = (const float*)d_in[6];
    const float* b2   = (const float*)d_in[7];
    const float* Wlin = (const float*)d_in[8];
    const float* blin = (const float*)d_in[9];
    float* outp = (float*)d_out;

    const int N = in_sizes[0] / F_IN;
    const int E = in_sizes[1] / 2;
    const int* srcv = ei;
    const int* dstv = ei + E;

    char* ws = (char*)d_ws;
    size_t o = 0;
    auto alloc = [&](size_t bytes) { size_t r = o; o += (bytes + 255) & ~(size_t)255; return r; };
    int* cnt_i  = (int*)(ws + alloc((size_t)N * 4));
    int* offs   = (int*)(ws + alloc((size_t)N * 4));
    int* cursor = (int*)(ws + alloc((size_t)N * 4));
    int* bsums  = (int*)(ws + alloc(1024));
    int* csr    = (int*)(ws + alloc((size_t)E * 4));
    short* xb   = (short*)(ws + alloc((size_t)N * KP1 * 2));   // reused for y2/h2 later
    short* wc1  = (short*)(ws + alloc((size_t)256 * KP1 * 2));
    short* wc2  = (short*)(ws + alloc((size_t)128 * 128 * 2));
    short* y1l  = (short*)(ws + alloc((size_t)N * H1 * 2));
    short* y1r  = (short*)(ws + alloc((size_t)N * H1 * 2));
    short* h1   = (short*)(ws + alloc((size_t)N * H1 * 2));
    // overlay layer-2 buffers onto xb (dead after G1): 3 * N*64*2 = N*192*2 bytes
    short* y2l  = xb;
    short* y2r  = xb + (size_t)N * H2;
    short* h2   = xb + (size_t)N * H2 * 2;

    const int eb = (E + 255) / 256;
    const int nb = (N + 2047) / 2048;
    const int nthr = (N + 255) / 256;
    const int gblk = (N + 63) / 64;
    const int ablk = (N + 7) / 8;

    // CSR build
    hipMemsetAsync(cnt_i, 0, (size_t)N * 4, stream);
    deg_count<<<eb, 256, 0, stream>>>(dstv, cnt_i, E);
    scan_block<<<nb, 256, 0, stream>>>(cnt_i, offs, bsums, N);
    scan_bsums<<<1, 64, 0, stream>>>(bsums, nb);
    scan_add<<<nthr, 256, 0, stream>>>(offs, cursor, bsums, N);
    csr_build<<<eb, 256, 0, stream>>>(srcv, dstv, cursor, csr, E);

    // conversions
    conv_x<<<(N + 3) / 4, 256, 0, stream>>>(x, xb, N);
    conv_w1<<<(256 * KP1 + 255) / 256, 256, 0, stream>>>(W1l, W1r, wc1);
    conv_w2<<<(128 * 128 + 255) / 256, 256, 0, stream>>>(W2l, W2r, wc2);

    // layer 1: y1 = x @ [W1l;W1r]^T  then fused agg+bias+relu
    gemm_mfma<256, KP1><<<gblk, 256, 0, stream>>>(xb, wc1, y1l, y1r, N);
    agg_fuse<H1><<<ablk, 256, 0, stream>>>(offs, cnt_i, csr, y1l, y1r, b1, h1, N);

    // layer 2 (y2/h2 overlay xb, which is dead now)
    gemm_mfma<128, 128><<<gblk, 256, 0, stream>>>(h1, wc2, y2l, y2r, N);
    agg_fuse<H2><<<ablk, 256, 0, stream>>>(offs, cnt_i, csr, y2l, y2r, b2, h2, N);

    // head
    head_lsm<<<ablk, 256, 0, stream>>>(h2, Wlin, blin, outp, N);
}

// Round 3
// 269.732 us; speedup vs baseline: 3.0212x; 1.1452x over previous
//
#include <hip/hip_runtime.h>
#include <math.h>

#define F_IN 182
#define KP1  192   // padded K for layer 1
#define H1   128
#define H2   64

typedef short bf16x8 __attribute__((ext_vector_type(8)));
typedef float f32x4 __attribute__((ext_vector_type(4)));

__device__ __forceinline__ float b2f(short s) {
    unsigned u = ((unsigned)(unsigned short)s) << 16;
    return __builtin_bit_cast(float, u);
}
__device__ __forceinline__ short f2b(float f) {
    unsigned u = __builtin_bit_cast(unsigned, f);
    unsigned r = (u + 0x7FFFu + ((u >> 16) & 1u)) >> 16;
    return (short)(unsigned short)r;
}

// ---------------- graph preprocessing ----------------
__global__ __launch_bounds__(256) void deg_count(const int* __restrict__ dst,
                                                 int* __restrict__ cnt, int E) {
    int e = blockIdx.x * 256 + threadIdx.x;
    if (e < E) atomicAdd(&cnt[dst[e]], 1);
}

__global__ __launch_bounds__(256) void scan_block(const int* __restrict__ in,
                                                  int* __restrict__ out,
                                                  int* __restrict__ bsums, int Nn) {
    __shared__ int s[256];
    int b = blockIdx.x, t = threadIdx.x;
    int base = b * 2048 + t * 8;
    int v[8]; int sum = 0;
#pragma unroll
    for (int i = 0; i < 8; ++i) { int idx = base + i; v[i] = (idx < Nn) ? in[idx] : 0; sum += v[i]; }
    s[t] = sum; __syncthreads();
    for (int off = 1; off < 256; off <<= 1) {
        int x = (t >= off) ? s[t - off] : 0; __syncthreads();
        s[t] += x; __syncthreads();
    }
    int excl = s[t] - sum;
    if (t == 255) bsums[b] = s[255];
    int run = excl;
#pragma unroll
    for (int i = 0; i < 8; ++i) { int idx = base + i; if (idx < Nn) out[idx] = run; run += v[i]; }
}

__global__ void scan_bsums(int* bs, int nb) {
    if (blockIdx.x == 0 && threadIdx.x == 0) {
        int run = 0;
        for (int i = 0; i < nb; ++i) { int x = bs[i]; bs[i] = run; run += x; }
    }
}

__global__ __launch_bounds__(256) void scan_add(int* __restrict__ offs,
                                                int* __restrict__ cursor,
                                                const int* __restrict__ bs, int Nn) {
    int i = blockIdx.x * 256 + threadIdx.x;
    if (i < Nn) { int o = offs[i] + bs[i >> 11]; offs[i] = o; cursor[i] = o; }
}

__global__ __launch_bounds__(256) void csr_build(const int* __restrict__ src,
                                                 const int* __restrict__ dst,
                                                 int* __restrict__ cursor,
                                                 int* __restrict__ csr, int E) {
    int e = blockIdx.x * 256 + threadIdx.x;
    if (e < E) {
        int p = atomicAdd(&cursor[dst[e]], 1);
        csr[p] = src[e];
    }
}

// ---------------- weight conversions ----------------
__global__ __launch_bounds__(256) void conv_w1(const float* __restrict__ Wl,
                                               const float* __restrict__ Wr,
                                               short* __restrict__ o) {
    int idx = blockIdx.x * 256 + threadIdx.x;
    if (idx >= 256 * KP1) return;
    int r = idx / KP1, k = idx - r * KP1;
    float v = 0.f;
    if (k < F_IN) v = (r < 128) ? Wl[r * F_IN + k] : Wr[(r - 128) * F_IN + k];
    o[idx] = f2b(v);
}

__global__ __launch_bounds__(256) void conv_w2(const float* __restrict__ Wl,
                                               const float* __restrict__ Wr,
                                               short* __restrict__ o) {
    int idx = blockIdx.x * 256 + threadIdx.x;
    if (idx >= 128 * 128) return;
    int r = idx >> 7, k = idx & 127;
    float v = (r < 64) ? Wl[r * 128 + k] : Wr[(r - 64) * 128 + k];
    o[idx] = f2b(v);
}

// ---------------- bf16 MFMA GEMM: y = A @ W^T, split output halves ----------------
// AF32: A is fp32 [M][KREAL], converted during staging (cols >= KREAL zero).
// else: A is bf16 [M][KK]. W: [NC][KK] bf16. outL/outR: [M][NC/2] bf16 each.
template <int NC, int KK, bool AF32, int KREAL>
__global__ __launch_bounds__(256) void gemm_mfma(const void* __restrict__ Ap,
                                                 const short* __restrict__ W,
                                                 short* __restrict__ outL,
                                                 short* __restrict__ outR, int M) {
    constexpr int BM = 64, BK = 64;
    constexpr int LDA = BK + 8;        // 144 B rows -> 2-way bank aliasing (free)
    constexpr int WN = NC / 4;
    constexpr int NJ = WN / 16;
    __shared__ __attribute__((aligned(16))) short sA[BM][LDA];
    __shared__ __attribute__((aligned(16))) short sB[NC][LDA];
    int tid = threadIdx.x;
    int wid = tid >> 6, lane = tid & 63;
    int row0 = blockIdx.x * BM;
    f32x4 acc[4][NJ] = {};
    for (int k0 = 0; k0 < KK; k0 += BK) {
        if (AF32) {
            const float* Af = (const float*)Ap;
            for (int c = tid; c < BM * (BK / 2); c += 256) {
                int r = c >> 5, k2 = (c & 31) * 2;
                int gr = row0 + r, gk = k0 + k2;
                float2 v = make_float2(0.f, 0.f);
                if (gr < M && gk < KREAL) v = *(const float2*)(Af + (size_t)gr * KREAL + gk);
                short2 o; o.x = f2b(v.x); o.y = f2b(v.y);
                *(short2*)(&sA[r][k2]) = o;
            }
        } else {
            const short* Ab = (const short*)Ap;
            for (int c = tid; c < BM * (BK / 8); c += 256) {
                int r = c >> 3, kc = (c & 7) * 8;
                int gr = row0 + r;
                bf16x8 v = {};
                if (gr < M) v = *(const bf16x8*)(Ab + (size_t)gr * KK + k0 + kc);
                *(bf16x8*)(&sA[r][kc]) = v;
            }
        }
        for (int c = tid; c < NC * (BK / 8); c += 256) {
            int r = c >> 3, kc = (c & 7) * 8;
            *(bf16x8*)(&sB[r][kc]) = *(const bf16x8*)(W + (size_t)r * KK + k0 + kc);
        }
        __syncthreads();
#pragma unroll
        for (int ks = 0; ks < 2; ++ks) {
            int kb = ks * 32 + (lane >> 4) * 8;
            bf16x8 af[4];
#pragma unroll
            for (int mi = 0; mi < 4; ++mi)
                af[mi] = *(const bf16x8*)(&sA[mi * 16 + (lane & 15)][kb]);
#pragma unroll
            for (int ni = 0; ni < NJ; ++ni) {
                bf16x8 bfr = *(const bf16x8*)(&sB[wid * WN + ni * 16 + (lane & 15)][kb]);
#pragma unroll
                for (int mi = 0; mi < 4; ++mi)
                    acc[mi][ni] = __builtin_amdgcn_mfma_f32_16x16x32_bf16(af[mi], bfr, acc[mi][ni], 0, 0, 0);
            }
        }
        __syncthreads();
    }
    constexpr int HN = NC / 2;
#pragma unroll
    for (int mi = 0; mi < 4; ++mi) {
#pragma unroll
        for (int ni = 0; ni < NJ; ++ni) {
            int gc = wid * WN + ni * 16 + (lane & 15);
#pragma unroll
            for (int r = 0; r < 4; ++r) {
                int gr = row0 + mi * 16 + (lane >> 4) * 4 + r;
                if (gr < M) {
                    short v = f2b(acc[mi][ni][r]);
                    if (gc < HN) outL[(size_t)gr * HN + gc] = v;
                    else         outR[(size_t)gr * HN + gc - HN] = v;
                }
            }
        }
    }
}

// ---------------- fused mean-aggregate + residual + bias + relu (layer 1) ----------------
__global__ __launch_bounds__(256) void agg_fuse1(const int* __restrict__ offs,
                                                 const int* __restrict__ degs,
                                                 const int* __restrict__ csr,
                                                 const short* __restrict__ yl,
                                                 const short* __restrict__ yr,
                                                 const float* __restrict__ bias,
                                                 short* __restrict__ h, int Nn) {
    int gid = blockIdx.x * 8 + (threadIdx.x >> 5);
    int l = threadIdx.x & 31;
    if (gid >= Nn) return;
    int start = offs[gid], deg = degs[gid];
    const size_t lo = (size_t)l * 4;
    float a0 = 0.f, a1 = 0.f, a2 = 0.f, a3 = 0.f;
    int t = 0;
    for (; t + 4 <= deg; t += 4) {
        int s0 = csr[start + t], s1 = csr[start + t + 1];
        int s2 = csr[start + t + 2], s3 = csr[start + t + 3];
        short4 v0 = *(const short4*)(yl + (size_t)s0 * H1 + lo);
        short4 v1 = *(const short4*)(yl + (size_t)s1 * H1 + lo);
        short4 v2 = *(const short4*)(yl + (size_t)s2 * H1 + lo);
        short4 v3 = *(const short4*)(yl + (size_t)s3 * H1 + lo);
        a0 += b2f(v0.x) + b2f(v1.x) + b2f(v2.x) + b2f(v3.x);
        a1 += b2f(v0.y) + b2f(v1.y) + b2f(v2.y) + b2f(v3.y);
        a2 += b2f(v0.z) + b2f(v1.z) + b2f(v2.z) + b2f(v3.z);
        a3 += b2f(v0.w) + b2f(v1.w) + b2f(v2.w) + b2f(v3.w);
    }
    for (; t < deg; ++t) {
        int s = csr[start + t];
        short4 v = *(const short4*)(yl + (size_t)s * H1 + lo);
        a0 += b2f(v.x); a1 += b2f(v.y); a2 += b2f(v.z); a3 += b2f(v.w);
    }
    float inv = 1.f / fmaxf((float)deg, 1.f);
    short4 rv = *(const short4*)(yr + (size_t)gid * H1 + lo);
    short4 o;
    o.x = f2b(fmaxf(a0 * inv + b2f(rv.x) + bias[l * 4 + 0], 0.f));
    o.y = f2b(fmaxf(a1 * inv + b2f(rv.y) + bias[l * 4 + 1], 0.f));
    o.z = f2b(fmaxf(a2 * inv + b2f(rv.z) + bias[l * 4 + 2], 0.f));
    o.w = f2b(fmaxf(a3 * inv + b2f(rv.w) + bias[l * 4 + 3], 0.f));
    *(short4*)(h + (size_t)gid * H1 + lo) = o;
}

// ------- fused mean-aggregate + residual + bias + relu + head + log_softmax (layer 2) -------
__global__ __launch_bounds__(256) void agg_head2(const int* __restrict__ offs,
                                                 const int* __restrict__ degs,
                                                 const int* __restrict__ csr,
                                                 const short* __restrict__ yl,
                                                 const short* __restrict__ yr,
                                                 const float* __restrict__ bias,
                                                 const float* __restrict__ Wlin,
                                                 const float* __restrict__ blin,
                                                 float* __restrict__ out, int Nn) {
    int gid = blockIdx.x * 8 + (threadIdx.x >> 5);
    int l = threadIdx.x & 31;
    if (gid >= Nn) return;
    int start = offs[gid], deg = degs[gid];
    const size_t lo = (size_t)l * 2;
    float a0 = 0.f, a1 = 0.f;
    int t = 0;
    for (; t + 4 <= deg; t += 4) {
        int s0 = csr[start + t], s1 = csr[start + t + 1];
        int s2 = csr[start + t + 2], s3 = csr[start + t + 3];
        short2 v0 = *(const short2*)(yl + (size_t)s0 * H2 + lo);
        short2 v1 = *(const short2*)(yl + (size_t)s1 * H2 + lo);
        short2 v2 = *(const short2*)(yl + (size_t)s2 * H2 + lo);
        short2 v3 = *(const short2*)(yl + (size_t)s3 * H2 + lo);
        a0 += b2f(v0.x) + b2f(v1.x) + b2f(v2.x) + b2f(v3.x);
        a1 += b2f(v0.y) + b2f(v1.y) + b2f(v2.y) + b2f(v3.y);
    }
    for (; t < deg; ++t) {
        int s = csr[start + t];
        short2 v = *(const short2*)(yl + (size_t)s * H2 + lo);
        a0 += b2f(v.x); a1 += b2f(v.y);
    }
    float inv = 1.f / fmaxf((float)deg, 1.f);
    short2 rv = *(const short2*)(yr + (size_t)gid * H2 + lo);
    float h0 = fmaxf(a0 * inv + b2f(rv.x) + bias[l * 2 + 0], 0.f);
    float h1v = fmaxf(a1 * inv + b2f(rv.y) + bias[l * 2 + 1], 0.f);
    // head: logits = h @ Wlin^T + blin  (C = 2)
    float g0 = h0 * Wlin[2 * l] + h1v * Wlin[2 * l + 1];
    float g1 = h0 * Wlin[64 + 2 * l] + h1v * Wlin[64 + 2 * l + 1];
#pragma unroll
    for (int m = 16; m >= 1; m >>= 1) {
        g0 += __shfl_xor(g0, m, 32);
        g1 += __shfl_xor(g1, m, 32);
    }
    if (l == 0) {
        g0 += blin[0]; g1 += blin[1];
        float mx = fmaxf(g0, g1);
        float lse = mx + logf(expf(g0 - mx) + expf(g1 - mx));
        float2 r; r.x = g0 - lse; r.y = g1 - lse;
        ((float2*)out)[gid] = r;
    }
}

extern "C" void kernel_launch(void* const* d_in, const int* in_sizes, int n_in,
                              void* d_out, int out_size, void* d_ws, size_t ws_size,
                              hipStream_t stream) {
    const float* x    = (const float*)d_in[0];
    const int*   ei   = (const int*)d_in[1];
    const float* W1l  = (const float*)d_in[2];
    const float* W1r  = (const float*)d_in[3];
    const float* b1   = (const float*)d_in[4];
    const float* W2l  = (const float*)d_in[5];
    const float* W2r  = (const float*)d_in[6];
    const float* b2   = (const float*)d_in[7];
    const float* Wlin = (const float*)d_in[8];
    const float* blin = (const float*)d_in[9];
    float* outp = (float*)d_out;

    const int N = in_sizes[0] / F_IN;
    const int E = in_sizes[1] / 2;
    const int* srcv = ei;
    const int* dstv = ei + E;

    char* ws = (char*)d_ws;
    size_t o = 0;
    auto alloc = [&](size_t bytes) { size_t r = o; o += (bytes + 255) & ~(size_t)255; return r; };
    int* cnt_i  = (int*)(ws + alloc((size_t)N * 4));
    int* offs   = (int*)(ws + alloc((size_t)N * 4));
    int* cursor = (int*)(ws + alloc((size_t)N * 4));
    int* bsums  = (int*)(ws + alloc(1024));
    int* csr    = (int*)(ws + alloc((size_t)E * 4));
    short* wc1  = (short*)(ws + alloc((size_t)256 * KP1 * 2));
    short* wc2  = (short*)(ws + alloc((size_t)128 * 128 * 2));
    short* y1l  = (short*)(ws + alloc((size_t)N * H1 * 2));
    short* y1r  = (short*)(ws + alloc((size_t)N * H1 * 2));
    short* h1   = (short*)(ws + alloc((size_t)N * H1 * 2));
    short* y2l  = (short*)(ws + alloc((size_t)N * H2 * 2));
    short* y2r  = (short*)(ws + alloc((size_t)N * H2 * 2));

    const int eb = (E + 255) / 256;
    const int nb = (N + 2047) / 2048;
    const int nthr = (N + 255) / 256;
    const int gblk = (N + 63) / 64;
    const int ablk = (N + 7) / 8;

    // CSR build
    hipMemsetAsync(cnt_i, 0, (size_t)N * 4, stream);
    deg_count<<<eb, 256, 0, stream>>>(dstv, cnt_i, E);
    scan_block<<<nb, 256, 0, stream>>>(cnt_i, offs, bsums, N);
    scan_bsums<<<1, 64, 0, stream>>>(bsums, nb);
    scan_add<<<nthr, 256, 0, stream>>>(offs, cursor, bsums, N);
    csr_build<<<eb, 256, 0, stream>>>(srcv, dstv, cursor, csr, E);

    // weight conversions
    conv_w1<<<(256 * KP1 + 255) / 256, 256, 0, stream>>>(W1l, W1r, wc1);
    conv_w2<<<(128 * 128 + 255) / 256, 256, 0, stream>>>(W2l, W2r, wc2);

    // layer 1: y1 = x @ [W1l;W1r]^T  (fp32 A converted in staging), then fused agg
    gemm_mfma<256, KP1, true, F_IN><<<gblk, 256, 0, stream>>>(x, wc1, y1l, y1r, N);
    agg_fuse1<<<ablk, 256, 0, stream>>>(offs, cnt_i, csr, y1l, y1r, b1, h1, N);

    // layer 2 + head fused
    gemm_mfma<128, 128, false, 128><<<gblk, 256, 0, stream>>>(h1, wc2, y2l, y2r, N);
    agg_head2<<<ablk, 256, 0, stream>>>(offs, cnt_i, csr, y2l, y2r, b2, Wlin, blin, outp, N);
}

// Round 4
// 259.383 us; speedup vs baseline: 3.1417x; 1.0399x over previous
//
#include <hip/hip_runtime.h>
#include <math.h>

#define F_IN 182
#define KP1  192   // padded K for layer 1
#define H1   128
#define H2   64

typedef short bf16x8 __attribute__((ext_vector_type(8)));
typedef float f32x4 __attribute__((ext_vector_type(4)));

__device__ __forceinline__ float b2f(short s) {
    unsigned u = ((unsigned)(unsigned short)s) << 16;
    return __builtin_bit_cast(float, u);
}
__device__ __forceinline__ short f2b(float f) {
    unsigned u = __builtin_bit_cast(unsigned, f);
    unsigned r = (u + 0x7FFFu + ((u >> 16) & 1u)) >> 16;
    return (short)(unsigned short)r;
}

// ---------------- graph preprocessing ----------------
__global__ __launch_bounds__(256) void deg_count(const int* __restrict__ dst,
                                                 int* __restrict__ cnt, int E) {
    int e = blockIdx.x * 256 + threadIdx.x;
    if (e < E) atomicAdd(&cnt[dst[e]], 1);
}

__global__ __launch_bounds__(256) void scan_block(const int* __restrict__ in,
                                                  int* __restrict__ out,
                                                  int* __restrict__ bsums, int Nn) {
    __shared__ int s[256];
    int b = blockIdx.x, t = threadIdx.x;
    int base = b * 2048 + t * 8;
    int v[8]; int sum = 0;
#pragma unroll
    for (int i = 0; i < 8; ++i) { int idx = base + i; v[i] = (idx < Nn) ? in[idx] : 0; sum += v[i]; }
    s[t] = sum; __syncthreads();
    for (int off = 1; off < 256; off <<= 1) {
        int x = (t >= off) ? s[t - off] : 0; __syncthreads();
        s[t] += x; __syncthreads();
    }
    int excl = s[t] - sum;
    if (t == 255) bsums[b] = s[255];
    int run = excl;
#pragma unroll
    for (int i = 0; i < 8; ++i) { int idx = base + i; if (idx < Nn) out[idx] = run; run += v[i]; }
}

__global__ void scan_bsums(int* bs, int nb) {
    if (blockIdx.x == 0 && threadIdx.x == 0) {
        int run = 0;
        for (int i = 0; i < nb; ++i) { int x = bs[i]; bs[i] = run; run += x; }
    }
}

__global__ __launch_bounds__(256) void scan_add(int* __restrict__ offs,
                                                int* __restrict__ cursor,
                                                const int* __restrict__ bs, int Nn) {
    int i = blockIdx.x * 256 + threadIdx.x;
    if (i < Nn) { int o = offs[i] + bs[i >> 11]; offs[i] = o; cursor[i] = o; }
}

__global__ __launch_bounds__(256) void csr_build(const int* __restrict__ src,
                                                 const int* __restrict__ dst,
                                                 int* __restrict__ cursor,
                                                 int* __restrict__ csr, int E) {
    int e = blockIdx.x * 256 + threadIdx.x;
    if (e < E) {
        int p = atomicAdd(&cursor[dst[e]], 1);
        csr[p] = src[e];
    }
}

// ---------------- conversions ----------------
// x fp32 [N][182] -> xb bf16 [N][192] (cols 182..191 zero). One thread per 8 cols.
__global__ __launch_bounds__(256) void conv_x(const float* __restrict__ x,
                                              short* __restrict__ xb, int total) {
    int idx = blockIdx.x * 256 + threadIdx.x;
    if (idx >= total) return;
    int row = idx / 24;
    int c8 = (idx - row * 24) * 8;
    const float* xr = x + (size_t)row * F_IN + c8;
    bf16x8 o;
    if (c8 + 8 <= F_IN) {
        float2 v0 = *(const float2*)(xr + 0);
        float2 v1 = *(const float2*)(xr + 2);
        float2 v2 = *(const float2*)(xr + 4);
        float2 v3 = *(const float2*)(xr + 6);
        o[0] = f2b(v0.x); o[1] = f2b(v0.y);
        o[2] = f2b(v1.x); o[3] = f2b(v1.y);
        o[4] = f2b(v2.x); o[5] = f2b(v2.y);
        o[6] = f2b(v3.x); o[7] = f2b(v3.y);
    } else {
#pragma unroll
        for (int i = 0; i < 8; ++i) {
            int c = c8 + i;
            o[i] = (c < F_IN) ? f2b(xr[i]) : (short)0;
        }
    }
    *(bf16x8*)(xb + (size_t)row * KP1 + c8) = o;
}

__global__ __launch_bounds__(256) void conv_w1(const float* __restrict__ Wl,
                                               const float* __restrict__ Wr,
                                               short* __restrict__ o) {
    int idx = blockIdx.x * 256 + threadIdx.x;
    if (idx >= 256 * KP1) return;
    int r = idx / KP1, k = idx - r * KP1;
    float v = 0.f;
    if (k < F_IN) v = (r < 128) ? Wl[r * F_IN + k] : Wr[(r - 128) * F_IN + k];
    o[idx] = f2b(v);
}

__global__ __launch_bounds__(256) void conv_w2(const float* __restrict__ Wl,
                                               const float* __restrict__ Wr,
                                               short* __restrict__ o) {
    int idx = blockIdx.x * 256 + threadIdx.x;
    if (idx >= 128 * 128) return;
    int r = idx >> 7, k = idx & 127;
    float v = (r < 64) ? Wl[r * 128 + k] : Wr[(r - 64) * 128 + k];
    o[idx] = f2b(v);
}

// ---------------- bf16 MFMA GEMM: y = A @ W^T, split output halves ----------------
// A: [M][KK] bf16. W: [NC][KK] bf16. outL/outR: [M][NC/2] bf16 each.
// BM=128, 512 threads = 8 waves (2 row-groups x 4 col-groups).
template <int NC, int KK>
__global__ __launch_bounds__(512) void gemm_mfma(const short* __restrict__ A,
                                                 const short* __restrict__ W,
                                                 short* __restrict__ outL,
                                                 short* __restrict__ outR, int M) {
    constexpr int BM = 128, BK = 64;
    constexpr int LDA = BK + 8;        // 144 B rows -> 2-way bank aliasing (free)
    constexpr int WN = NC / 4;         // cols per wave
    constexpr int NJ = WN / 16;        // 16-col frags per wave
    __shared__ __attribute__((aligned(16))) short sA[BM][LDA];
    __shared__ __attribute__((aligned(16))) short sB[NC][LDA];
    int tid = threadIdx.x;
    int wid = tid >> 6, lane = tid & 63;
    int wr = wid >> 2, wc = wid & 3;
    int row0 = blockIdx.x * BM;
    f32x4 acc[4][NJ] = {};
    for (int k0 = 0; k0 < KK; k0 += BK) {
        for (int c = tid; c < BM * (BK / 8); c += 512) {
            int r = c >> 3, kc = (c & 7) * 8;
            int gr = row0 + r;
            bf16x8 v = {};
            if (gr < M) v = *(const bf16x8*)(A + (size_t)gr * KK + k0 + kc);
            *(bf16x8*)(&sA[r][kc]) = v;
        }
        for (int c = tid; c < NC * (BK / 8); c += 512) {
            int r = c >> 3, kc = (c & 7) * 8;
            *(bf16x8*)(&sB[r][kc]) = *(const bf16x8*)(W + (size_t)r * KK + k0 + kc);
        }
        __syncthreads();
#pragma unroll
        for (int ks = 0; ks < 2; ++ks) {
            int kb = ks * 32 + (lane >> 4) * 8;
            bf16x8 af[4];
#pragma unroll
            for (int mi = 0; mi < 4; ++mi)
                af[mi] = *(const bf16x8*)(&sA[wr * 64 + mi * 16 + (lane & 15)][kb]);
#pragma unroll
            for (int ni = 0; ni < NJ; ++ni) {
                bf16x8 bfr = *(const bf16x8*)(&sB[wc * WN + ni * 16 + (lane & 15)][kb]);
#pragma unroll
                for (int mi = 0; mi < 4; ++mi)
                    acc[mi][ni] = __builtin_amdgcn_mfma_f32_16x16x32_bf16(af[mi], bfr, acc[mi][ni], 0, 0, 0);
            }
        }
        __syncthreads();
    }
    constexpr int HN = NC / 2;
#pragma unroll
    for (int mi = 0; mi < 4; ++mi) {
#pragma unroll
        for (int ni = 0; ni < NJ; ++ni) {
            int gc = wc * WN + ni * 16 + (lane & 15);
#pragma unroll
            for (int r = 0; r < 4; ++r) {
                int gr = row0 + wr * 64 + mi * 16 + (lane >> 4) * 4 + r;
                if (gr < M) {
                    short v = f2b(acc[mi][ni][r]);
                    if (gc < HN) outL[(size_t)gr * HN + gc] = v;
                    else         outR[(size_t)gr * HN + gc - HN] = v;
                }
            }
        }
    }
}

// ---------------- fused mean-aggregate + residual + bias + relu (layer 1) ----------------
__global__ __launch_bounds__(256) void agg_fuse1(const int* __restrict__ offs,
                                                 const int* __restrict__ degs,
                                                 const int* __restrict__ csr,
                                                 const short* __restrict__ yl,
                                                 const short* __restrict__ yr,
                                                 const float* __restrict__ bias,
                                                 short* __restrict__ h, int Nn) {
    int gid = blockIdx.x * 8 + (threadIdx.x >> 5);
    int l = threadIdx.x & 31;
    if (gid >= Nn) return;
    int start = offs[gid], deg = degs[gid];
    const size_t lo = (size_t)l * 4;
    float a0 = 0.f, a1 = 0.f, a2 = 0.f, a3 = 0.f;
    int t = 0;
    for (; t + 4 <= deg; t += 4) {
        int s0 = csr[start + t], s1 = csr[start + t + 1];
        int s2 = csr[start + t + 2], s3 = csr[start + t + 3];
        short4 v0 = *(const short4*)(yl + (size_t)s0 * H1 + lo);
        short4 v1 = *(const short4*)(yl + (size_t)s1 * H1 + lo);
        short4 v2 = *(const short4*)(yl + (size_t)s2 * H1 + lo);
        short4 v3 = *(const short4*)(yl + (size_t)s3 * H1 + lo);
        a0 += b2f(v0.x) + b2f(v1.x) + b2f(v2.x) + b2f(v3.x);
        a1 += b2f(v0.y) + b2f(v1.y) + b2f(v2.y) + b2f(v3.y);
        a2 += b2f(v0.z) + b2f(v1.z) + b2f(v2.z) + b2f(v3.z);
        a3 += b2f(v0.w) + b2f(v1.w) + b2f(v2.w) + b2f(v3.w);
    }
    for (; t < deg; ++t) {
        int s = csr[start + t];
        short4 v = *(const short4*)(yl + (size_t)s * H1 + lo);
        a0 += b2f(v.x); a1 += b2f(v.y); a2 += b2f(v.z); a3 += b2f(v.w);
    }
    float inv = 1.f / fmaxf((float)deg, 1.f);
    short4 rv = *(const short4*)(yr + (size_t)gid * H1 + lo);
    short4 o;
    o.x = f2b(fmaxf(a0 * inv + b2f(rv.x) + bias[l * 4 + 0], 0.f));
    o.y = f2b(fmaxf(a1 * inv + b2f(rv.y) + bias[l * 4 + 1], 0.f));
    o.z = f2b(fmaxf(a2 * inv + b2f(rv.z) + bias[l * 4 + 2], 0.f));
    o.w = f2b(fmaxf(a3 * inv + b2f(rv.w) + bias[l * 4 + 3], 0.f));
    *(short4*)(h + (size_t)gid * H1 + lo) = o;
}

// ------- fused mean-aggregate + residual + bias + relu + head + log_softmax (layer 2) -------
__global__ __launch_bounds__(256) void agg_head2(const int* __restrict__ offs,
                                                 const int* __restrict__ degs,
                                                 const int* __restrict__ csr,
                                                 const short* __restrict__ yl,
                                                 const short* __restrict__ yr,
                                                 const float* __restrict__ bias,
                                                 const float* __restrict__ Wlin,
                                                 const float* __restrict__ blin,
                                                 float* __restrict__ out, int Nn) {
    int gid = blockIdx.x * 8 + (threadIdx.x >> 5);
    int l = threadIdx.x & 31;
    if (gid >= Nn) return;
    int start = offs[gid], deg = degs[gid];
    const size_t lo = (size_t)l * 2;
    float a0 = 0.f, a1 = 0.f;
    int t = 0;
    for (; t + 4 <= deg; t += 4) {
        int s0 = csr[start + t], s1 = csr[start + t + 1];
        int s2 = csr[start + t + 2], s3 = csr[start + t + 3];
        short2 v0 = *(const short2*)(yl + (size_t)s0 * H2 + lo);
        short2 v1 = *(const short2*)(yl + (size_t)s1 * H2 + lo);
        short2 v2 = *(const short2*)(yl + (size_t)s2 * H2 + lo);
        short2 v3 = *(const short2*)(yl + (size_t)s3 * H2 + lo);
        a0 += b2f(v0.x) + b2f(v1.x) + b2f(v2.x) + b2f(v3.x);
        a1 += b2f(v0.y) + b2f(v1.y) + b2f(v2.y) + b2f(v3.y);
    }
    for (; t < deg; ++t) {
        int s = csr[start + t];
        short2 v = *(const short2*)(yl + (size_t)s * H2 + lo);
        a0 += b2f(v.x); a1 += b2f(v.y);
    }
    float inv = 1.f / fmaxf((float)deg, 1.f);
    short2 rv = *(const short2*)(yr + (size_t)gid * H2 + lo);
    float h0 = fmaxf(a0 * inv + b2f(rv.x) + bias[l * 2 + 0], 0.f);
    float h1v = fmaxf(a1 * inv + b2f(rv.y) + bias[l * 2 + 1], 0.f);
    float g0 = h0 * Wlin[2 * l] + h1v * Wlin[2 * l + 1];
    float g1 = h0 * Wlin[64 + 2 * l] + h1v * Wlin[64 + 2 * l + 1];
#pragma unroll
    for (int m = 16; m >= 1; m >>= 1) {
        g0 += __shfl_xor(g0, m, 32);
        g1 += __shfl_xor(g1, m, 32);
    }
    if (l == 0) {
        g0 += blin[0]; g1 += blin[1];
        float mx = fmaxf(g0, g1);
        float lse = mx + logf(expf(g0 - mx) + expf(g1 - mx));
        float2 r; r.x = g0 - lse; r.y = g1 - lse;
        ((float2*)out)[gid] = r;
    }
}

extern "C" void kernel_launch(void* const* d_in, const int* in_sizes, int n_in,
                              void* d_out, int out_size, void* d_ws, size_t ws_size,
                              hipStream_t stream) {
    const float* x    = (const float*)d_in[0];
    const int*   ei   = (const int*)d_in[1];
    const float* W1l  = (const float*)d_in[2];
    const float* W1r  = (const float*)d_in[3];
    const float* b1   = (const float*)d_in[4];
    const float* W2l  = (const float*)d_in[5];
    const float* W2r  = (const float*)d_in[6];
    const float* b2   = (const float*)d_in[7];
    const float* Wlin = (const float*)d_in[8];
    const float* blin = (const float*)d_in[9];
    float* outp = (float*)d_out;

    const int N = in_sizes[0] / F_IN;
    const int E = in_sizes[1] / 2;
    const int* srcv = ei;
    const int* dstv = ei + E;

    char* ws = (char*)d_ws;
    size_t o = 0;
    auto alloc = [&](size_t bytes) { size_t r = o; o += (bytes + 255) & ~(size_t)255; return r; };
    int* cnt_i  = (int*)(ws + alloc((size_t)N * 4));
    int* offs   = (int*)(ws + alloc((size_t)N * 4));
    int* cursor = (int*)(ws + alloc((size_t)N * 4));
    int* bsums  = (int*)(ws + alloc(1024));
    int* csr    = (int*)(ws + alloc((size_t)E * 4));
    short* xb   = (short*)(ws + alloc((size_t)N * KP1 * 2));
    short* wc1  = (short*)(ws + alloc((size_t)256 * KP1 * 2));
    short* wc2  = (short*)(ws + alloc((size_t)128 * 128 * 2));
    short* y1l  = (short*)(ws + alloc((size_t)N * H1 * 2));
    short* y1r  = (short*)(ws + alloc((size_t)N * H1 * 2));
    short* h1   = (short*)(ws + alloc((size_t)N * H1 * 2));
    // layer-2 buffers overlay xb (dead after GEMM1)
    short* y2l  = xb;
    short* y2r  = xb + (size_t)N * H2;

    const int eb = (E + 255) / 256;
    const int nb = (N + 2047) / 2048;
    const int nthr = (N + 255) / 256;
    const int gblk = (N + 127) / 128;
    const int ablk = (N + 7) / 8;

    // CSR build
    hipMemsetAsync(cnt_i, 0, (size_t)N * 4, stream);
    deg_count<<<eb, 256, 0, stream>>>(dstv, cnt_i, E);
    scan_block<<<nb, 256, 0, stream>>>(cnt_i, offs, bsums, N);
    scan_bsums<<<1, 64, 0, stream>>>(bsums, nb);
    scan_add<<<nthr, 256, 0, stream>>>(offs, cursor, bsums, N);
    csr_build<<<eb, 256, 0, stream>>>(srcv, dstv, cursor, csr, E);

    // conversions
    conv_x<<<(N * 24 + 255) / 256, 256, 0, stream>>>(x, xb, N * 24);
    conv_w1<<<(256 * KP1 + 255) / 256, 256, 0, stream>>>(W1l, W1r, wc1);
    conv_w2<<<(128 * 128 + 255) / 256, 256, 0, stream>>>(W2l, W2r, wc2);

    // layer 1
    gemm_mfma<256, KP1><<<gblk, 512, 0, stream>>>(xb, wc1, y1l, y1r, N);
    agg_fuse1<<<ablk, 256, 0, stream>>>(offs, cnt_i, csr, y1l, y1r, b1, h1, N);

    // layer 2 + head fused (y2 overlays xb, dead after GEMM1)
    gemm_mfma<128, 128><<<gblk, 512, 0, stream>>>(h1, wc2, y2l, y2r, N);
    agg_head2<<<ablk, 256, 0, stream>>>(offs, cnt_i, csr, y2l, y2r, b2, Wlin, blin, outp, N);
}

// Round 5
// 249.847 us; speedup vs baseline: 3.2616x; 1.0382x over previous
//
#include <hip/hip_runtime.h>
#include <math.h>

#define F_IN 182
#define KP1  192   // padded K for layer 1
#define H1   128
#define H2   64

typedef short bf16x8 __attribute__((ext_vector_type(8)));
typedef float f32x4 __attribute__((ext_vector_type(4)));

__device__ __forceinline__ float b2f(short s) {
    unsigned u = ((unsigned)(unsigned short)s) << 16;
    return __builtin_bit_cast(float, u);
}
__device__ __forceinline__ short f2b(float f) {
    unsigned u = __builtin_bit_cast(unsigned, f);
    unsigned r = (u + 0x7FFFu + ((u >> 16) & 1u)) >> 16;
    return (short)(unsigned short)r;
}

#define GLOAD16(g, l) __builtin_amdgcn_global_load_lds( \
    (const __attribute__((address_space(1))) void*)(g), \
    (__attribute__((address_space(3))) void*)(l), 16, 0, 0)

// ---------------- graph preprocessing ----------------
__global__ __launch_bounds__(256) void deg_count4(const int* __restrict__ dst,
                                                  int* __restrict__ cnt, int E) {
    int base = (blockIdx.x * 256 + threadIdx.x) * 4;
    if (base + 4 <= E) {
        int4 d = *(const int4*)(dst + base);
        atomicAdd(&cnt[d.x], 1);
        atomicAdd(&cnt[d.y], 1);
        atomicAdd(&cnt[d.z], 1);
        atomicAdd(&cnt[d.w], 1);
    } else {
        for (int e = base; e < E; ++e) atomicAdd(&cnt[dst[e]], 1);
    }
}

__global__ __launch_bounds__(256) void scan_block(const int* __restrict__ in,
                                                  int* __restrict__ out,
                                                  int* __restrict__ bsums, int Nn) {
    __shared__ int s[256];
    int b = blockIdx.x, t = threadIdx.x;
    int base = b * 2048 + t * 8;
    int v[8]; int sum = 0;
#pragma unroll
    for (int i = 0; i < 8; ++i) { int idx = base + i; v[i] = (idx < Nn) ? in[idx] : 0; sum += v[i]; }
    s[t] = sum; __syncthreads();
    for (int off = 1; off < 256; off <<= 1) {
        int x = (t >= off) ? s[t - off] : 0; __syncthreads();
        s[t] += x; __syncthreads();
    }
    int excl = s[t] - sum;
    if (t == 255) bsums[b] = s[255];
    int run = excl;
#pragma unroll
    for (int i = 0; i < 8; ++i) { int idx = base + i; if (idx < Nn) out[idx] = run; run += v[i]; }
}

__global__ void scan_bsums(int* bs, int nb) {
    if (blockIdx.x == 0 && threadIdx.x == 0) {
        int run = 0;
        for (int i = 0; i < nb; ++i) { int x = bs[i]; bs[i] = run; run += x; }
    }
}

__global__ __launch_bounds__(256) void scan_add(int* __restrict__ offs,
                                                int* __restrict__ cursor,
                                                const int* __restrict__ bs, int Nn) {
    int i = blockIdx.x * 256 + threadIdx.x;
    if (i < Nn) { int o = offs[i] + bs[i >> 11]; offs[i] = o; cursor[i] = o; }
}

__global__ __launch_bounds__(256) void csr_build4(const int* __restrict__ src,
                                                  const int* __restrict__ dst,
                                                  int* __restrict__ cursor,
                                                  int* __restrict__ csr, int E) {
    int base = (blockIdx.x * 256 + threadIdx.x) * 4;
    if (base + 4 <= E) {
        int4 d = *(const int4*)(dst + base);
        int4 s = *(const int4*)(src + base);
        int p0 = atomicAdd(&cursor[d.x], 1);
        int p1 = atomicAdd(&cursor[d.y], 1);
        int p2 = atomicAdd(&cursor[d.z], 1);
        int p3 = atomicAdd(&cursor[d.w], 1);
        csr[p0] = s.x; csr[p1] = s.y; csr[p2] = s.z; csr[p3] = s.w;
    } else {
        for (int e = base; e < E; ++e) { int p = atomicAdd(&cursor[dst[e]], 1); csr[p] = src[e]; }
    }
}

// ---------------- conversions ----------------
__global__ __launch_bounds__(256) void conv_x(const float* __restrict__ x,
                                              short* __restrict__ xb, int total) {
    int idx = blockIdx.x * 256 + threadIdx.x;
    if (idx >= total) return;
    int row = idx / 24;
    int c8 = (idx - row * 24) * 8;
    const float* xr = x + (size_t)row * F_IN + c8;
    bf16x8 o;
    if (c8 + 8 <= F_IN) {
        float2 v0 = *(const float2*)(xr + 0);
        float2 v1 = *(const float2*)(xr + 2);
        float2 v2 = *(const float2*)(xr + 4);
        float2 v3 = *(const float2*)(xr + 6);
        o[0] = f2b(v0.x); o[1] = f2b(v0.y);
        o[2] = f2b(v1.x); o[3] = f2b(v1.y);
        o[4] = f2b(v2.x); o[5] = f2b(v2.y);
        o[6] = f2b(v3.x); o[7] = f2b(v3.y);
    } else {
#pragma unroll
        for (int i = 0; i < 8; ++i) {
            int c = c8 + i;
            o[i] = (c < F_IN) ? f2b(xr[i]) : (short)0;
        }
    }
    *(bf16x8*)(xb + (size_t)row * KP1 + c8) = o;
}

__global__ __launch_bounds__(256) void conv_w1(const float* __restrict__ Wl,
                                               const float* __restrict__ Wr,
                                               short* __restrict__ o) {
    int idx = blockIdx.x * 256 + threadIdx.x;
    if (idx >= 256 * KP1) return;
    int r = idx / KP1, k = idx - r * KP1;
    float v = 0.f;
    if (k < F_IN) v = (r < 128) ? Wl[r * F_IN + k] : Wr[(r - 128) * F_IN + k];
    o[idx] = f2b(v);
}

__global__ __launch_bounds__(256) void conv_w2(const float* __restrict__ Wl,
                                               const float* __restrict__ Wr,
                                               short* __restrict__ o) {
    int idx = blockIdx.x * 256 + threadIdx.x;
    if (idx >= 128 * 128) return;
    int r = idx >> 7, k = idx & 127;
    float v = (r < 64) ? Wl[r * 128 + k] : Wr[(r - 64) * 128 + k];
    o[idx] = f2b(v);
}

// ---------------- bf16 MFMA GEMM: y = A @ W^T, split output halves ----------------
// A: [M][KK] bf16, W: [NC][KK] bf16. outL/outR: [M][NC/2] bf16.
// BM=128, 512 threads = 8 waves (2 row x 4 col). global_load_lds staging with
// XOR-swizzled LDS layout: lds_byte(row, col) = row*128 + (col ^ ((row&7)<<4)).
template <int NC, int KK>
__global__ __launch_bounds__(512) void gemm_mfma(const short* __restrict__ A,
                                                 const short* __restrict__ W,
                                                 short* __restrict__ outL,
                                                 short* __restrict__ outR, int M) {
    constexpr int BM = 128, BK = 64;
    constexpr int WN = NC / 4;         // cols per wave
    constexpr int NJ = WN / 16;        // 16-col frags per wave
    constexpr int CA = BM / 64;        // gload calls per wave for A (1KB each): 2
    constexpr int CB = NC / 64;        // for B: 4 (NC=256) or 2 (NC=128)
    __shared__ __attribute__((aligned(16))) short sA[BM * BK];
    __shared__ __attribute__((aligned(16))) short sB[NC * BK];
    int tid = threadIdx.x;
    int wid = tid >> 6, lane = tid & 63;
    int wr = wid >> 2, wc = wid & 3;
    int row0 = blockIdx.x * BM;
    bool full = (row0 + BM <= M);
    const char* Ab = (const char*)A;
    const char* Wb = (const char*)W;
    f32x4 acc[4][NJ] = {};
    for (int k0 = 0; k0 < KK; k0 += BK) {
        if (full) {
            // direct global->LDS, source pre-swizzled so linear dest = swizzled layout
#pragma unroll
            for (int c = 0; c < CA; ++c) {
                int idx = (wid * CA + c) * 64 + lane;
                int r = idx >> 3, cs = (idx & 7) * 16;
                const char* g = Ab + (size_t)(row0 + r) * (KK * 2) + k0 * 2 + (cs ^ ((r & 7) << 4));
                GLOAD16(g, (char*)sA + (size_t)(wid * CA + c) * 1024);
            }
#pragma unroll
            for (int c = 0; c < CB; ++c) {
                int idx = (wid * CB + c) * 64 + lane;
                int r = idx >> 3, cs = (idx & 7) * 16;
                const char* g = Wb + (size_t)r * (KK * 2) + k0 * 2 + (cs ^ ((r & 7) << 4));
                GLOAD16(g, (char*)sB + (size_t)(wid * CB + c) * 1024);
            }
        } else {
            // tail block: guarded reg-staging into same swizzled layout
            for (int t = tid; t < BM * 8; t += 512) {
                int r = t >> 3, kc = (t & 7) * 16;
                bf16x8 v = {};
                int gr = row0 + r;
                if (gr < M) v = *(const bf16x8*)(Ab + (size_t)gr * (KK * 2) + k0 * 2 + kc);
                *(bf16x8*)((char*)sA + r * 128 + (kc ^ ((r & 7) << 4))) = v;
            }
            for (int t = tid; t < NC * 8; t += 512) {
                int r = t >> 3, kc = (t & 7) * 16;
                bf16x8 v = *(const bf16x8*)(Wb + (size_t)r * (KK * 2) + k0 * 2 + kc);
                *(bf16x8*)((char*)sB + r * 128 + (kc ^ ((r & 7) << 4))) = v;
            }
        }
        __syncthreads();
        int rl = lane & 15;
        int sw = (rl & 7) << 4;
#pragma unroll
        for (int ks = 0; ks < 2; ++ks) {
            int kb2 = ks * 64 + (lane >> 4) * 16;   // byte col within row
            int cswz = kb2 ^ sw;
            bf16x8 af[4];
#pragma unroll
            for (int mi = 0; mi < 4; ++mi) {
                int row = wr * 64 + mi * 16 + rl;
                af[mi] = *(const bf16x8*)((const char*)sA + row * 128 + cswz);
            }
#pragma unroll
            for (int ni = 0; ni < NJ; ++ni) {
                int rowb = wc * WN + ni * 16 + rl;
                bf16x8 bfr = *(const bf16x8*)((const char*)sB + rowb * 128 + cswz);
#pragma unroll
                for (int mi = 0; mi < 4; ++mi)
                    acc[mi][ni] = __builtin_amdgcn_mfma_f32_16x16x32_bf16(af[mi], bfr, acc[mi][ni], 0, 0, 0);
            }
        }
        __syncthreads();
    }
    constexpr int HN = NC / 2;
#pragma unroll
    for (int mi = 0; mi < 4; ++mi) {
#pragma unroll
        for (int ni = 0; ni < NJ; ++ni) {
            int gc = wc * WN + ni * 16 + (lane & 15);
#pragma unroll
            for (int r = 0; r < 4; ++r) {
                int gr = row0 + wr * 64 + mi * 16 + (lane >> 4) * 4 + r;
                if (gr < M) {
                    short v = f2b(acc[mi][ni][r]);
                    if (gc < HN) outL[(size_t)gr * HN + gc] = v;
                    else         outR[(size_t)gr * HN + gc - HN] = v;
                }
            }
        }
    }
}

// ---------------- fused mean-aggregate + residual + bias + relu (layer 1) ----------------
__global__ __launch_bounds__(256) void agg_fuse1(const int* __restrict__ offs,
                                                 const int* __restrict__ degs,
                                                 const int* __restrict__ csr,
                                                 const short* __restrict__ yl,
                                                 const short* __restrict__ yr,
                                                 const float* __restrict__ bias,
                                                 short* __restrict__ h, int Nn) {
    int gid = blockIdx.x * 8 + (threadIdx.x >> 5);
    int l = threadIdx.x & 31;
    if (gid >= Nn) return;
    int start = offs[gid], deg = degs[gid];
    const size_t lo = (size_t)l * 4;
    float a0 = 0.f, a1 = 0.f, a2 = 0.f, a3 = 0.f;
    int t = 0;
    for (; t + 4 <= deg; t += 4) {
        int s0 = csr[start + t], s1 = csr[start + t + 1];
        int s2 = csr[start + t + 2], s3 = csr[start + t + 3];
        short4 v0 = *(const short4*)(yl + (size_t)s0 * H1 + lo);
        short4 v1 = *(const short4*)(yl + (size_t)s1 * H1 + lo);
        short4 v2 = *(const short4*)(yl + (size_t)s2 * H1 + lo);
        short4 v3 = *(const short4*)(yl + (size_t)s3 * H1 + lo);
        a0 += b2f(v0.x) + b2f(v1.x) + b2f(v2.x) + b2f(v3.x);
        a1 += b2f(v0.y) + b2f(v1.y) + b2f(v2.y) + b2f(v3.y);
        a2 += b2f(v0.z) + b2f(v1.z) + b2f(v2.z) + b2f(v3.z);
        a3 += b2f(v0.w) + b2f(v1.w) + b2f(v2.w) + b2f(v3.w);
    }
    for (; t < deg; ++t) {
        int s = csr[start + t];
        short4 v = *(const short4*)(yl + (size_t)s * H1 + lo);
        a0 += b2f(v.x); a1 += b2f(v.y); a2 += b2f(v.z); a3 += b2f(v.w);
    }
    float inv = 1.f / fmaxf((float)deg, 1.f);
    short4 rv = *(const short4*)(yr + (size_t)gid * H1 + lo);
    short4 o;
    o.x = f2b(fmaxf(a0 * inv + b2f(rv.x) + bias[l * 4 + 0], 0.f));
    o.y = f2b(fmaxf(a1 * inv + b2f(rv.y) + bias[l * 4 + 1], 0.f));
    o.z = f2b(fmaxf(a2 * inv + b2f(rv.z) + bias[l * 4 + 2], 0.f));
    o.w = f2b(fmaxf(a3 * inv + b2f(rv.w) + bias[l * 4 + 3], 0.f));
    *(short4*)(h + (size_t)gid * H1 + lo) = o;
}

// ------- fused mean-aggregate + residual + bias + relu + head + log_softmax (layer 2) -------
__global__ __launch_bounds__(256) void agg_head2(const int* __restrict__ offs,
                                                 const int* __restrict__ degs,
                                                 const int* __restrict__ csr,
                                                 const short* __restrict__ yl,
                                                 const short* __restrict__ yr,
                                                 const float* __restrict__ bias,
                                                 const float* __restrict__ Wlin,
                                                 const float* __restrict__ blin,
                                                 float* __restrict__ out, int Nn) {
    int gid = blockIdx.x * 8 + (threadIdx.x >> 5);
    int l = threadIdx.x & 31;
    if (gid >= Nn) return;
    int start = offs[gid], deg = degs[gid];
    const size_t lo = (size_t)l * 2;
    float a0 = 0.f, a1 = 0.f;
    int t = 0;
    for (; t + 4 <= deg; t += 4) {
        int s0 = csr[start + t], s1 = csr[start + t + 1];
        int s2 = csr[start + t + 2], s3 = csr[start + t + 3];
        short2 v0 = *(const short2*)(yl + (size_t)s0 * H2 + lo);
        short2 v1 = *(const short2*)(yl + (size_t)s1 * H2 + lo);
        short2 v2 = *(const short2*)(yl + (size_t)s2 * H2 + lo);
        short2 v3 = *(const short2*)(yl + (size_t)s3 * H2 + lo);
        a0 += b2f(v0.x) + b2f(v1.x) + b2f(v2.x) + b2f(v3.x);
        a1 += b2f(v0.y) + b2f(v1.y) + b2f(v2.y) + b2f(v3.y);
    }
    for (; t < deg; ++t) {
        int s = csr[start + t];
        short2 v = *(const short2*)(yl + (size_t)s * H2 + lo);
        a0 += b2f(v.x); a1 += b2f(v.y);
    }
    float inv = 1.f / fmaxf((float)deg, 1.f);
    short2 rv = *(const short2*)(yr + (size_t)gid * H2 + lo);
    float h0 = fmaxf(a0 * inv + b2f(rv.x) + bias[l * 2 + 0], 0.f);
    float h1v = fmaxf(a1 * inv + b2f(rv.y) + bias[l * 2 + 1], 0.f);
    float g0 = h0 * Wlin[2 * l] + h1v * Wlin[2 * l + 1];
    float g1 = h0 * Wlin[64 + 2 * l] + h1v * Wlin[64 + 2 * l + 1];
#pragma unroll
    for (int m = 16; m >= 1; m >>= 1) {
        g0 += __shfl_xor(g0, m, 32);
        g1 += __shfl_xor(g1, m, 32);
    }
    if (l == 0) {
        g0 += blin[0]; g1 += blin[1];
        float mx = fmaxf(g0, g1);
        float lse = mx + logf(expf(g0 - mx) + expf(g1 - mx));
        float2 r; r.x = g0 - lse; r.y = g1 - lse;
        ((float2*)out)[gid] = r;
    }
}

extern "C" void kernel_launch(void* const* d_in, const int* in_sizes, int n_in,
                              void* d_out, int out_size, void* d_ws, size_t ws_size,
                              hipStream_t stream) {
    const float* x    = (const float*)d_in[0];
    const int*   ei   = (const int*)d_in[1];
    const float* W1l  = (const float*)d_in[2];
    const float* W1r  = (const float*)d_in[3];
    const float* b1   = (const float*)d_in[4];
    const float* W2l  = (const float*)d_in[5];
    const float* W2r  = (const float*)d_in[6];
    const float* b2   = (const float*)d_in[7];
    const float* Wlin = (const float*)d_in[8];
    const float* blin = (const float*)d_in[9];
    float* outp = (float*)d_out;

    const int N = in_sizes[0] / F_IN;
    const int E = in_sizes[1] / 2;
    const int* srcv = ei;
    const int* dstv = ei + E;

    char* ws = (char*)d_ws;
    size_t o = 0;
    auto alloc = [&](size_t bytes) { size_t r = o; o += (bytes + 255) & ~(size_t)255; return r; };
    int* cnt_i  = (int*)(ws + alloc((size_t)N * 4));
    int* offs   = (int*)(ws + alloc((size_t)N * 4));
    int* cursor = (int*)(ws + alloc((size_t)N * 4));
    int* bsums  = (int*)(ws + alloc(1024));
    int* csr    = (int*)(ws + alloc((size_t)E * 4));
    short* xb   = (short*)(ws + alloc((size_t)N * KP1 * 2));
    short* wc1  = (short*)(ws + alloc((size_t)256 * KP1 * 2));
    short* wc2  = (short*)(ws + alloc((size_t)128 * 128 * 2));
    short* y1l  = (short*)(ws + alloc((size_t)N * H1 * 2));
    short* y1r  = (short*)(ws + alloc((size_t)N * H1 * 2));
    short* h1   = (short*)(ws + alloc((size_t)N * H1 * 2));
    // layer-2 buffers overlay xb (dead after GEMM1)
    short* y2l  = xb;
    short* y2r  = xb + (size_t)N * H2;

    const int e4 = (E + 1023) / 1024;
    const int nb = (N + 2047) / 2048;
    const int nthr = (N + 255) / 256;
    const int gblk = (N + 127) / 128;
    const int ablk = (N + 7) / 8;

    // CSR build
    hipMemsetAsync(cnt_i, 0, (size_t)N * 4, stream);
    deg_count4<<<e4, 256, 0, stream>>>(dstv, cnt_i, E);
    scan_block<<<nb, 256, 0, stream>>>(cnt_i, offs, bsums, N);
    scan_bsums<<<1, 64, 0, stream>>>(bsums, nb);
    scan_add<<<nthr, 256, 0, stream>>>(offs, cursor, bsums, N);
    csr_build4<<<e4, 256, 0, stream>>>(srcv, dstv, cursor, csr, E);

    // conversions
    conv_x<<<(N * 24 + 255) / 256, 256, 0, stream>>>(x, xb, N * 24);
    conv_w1<<<(256 * KP1 + 255) / 256, 256, 0, stream>>>(W1l, W1r, wc1);
    conv_w2<<<(128 * 128 + 255) / 256, 256, 0, stream>>>(W2l, W2r, wc2);

    // layer 1
    gemm_mfma<256, KP1><<<gblk, 512, 0, stream>>>(xb, wc1, y1l, y1r, N);
    agg_fuse1<<<ablk, 256, 0, stream>>>(offs, cnt_i, csr, y1l, y1r, b1, h1, N);

    // layer 2 + head fused (y2 overlays xb, dead after GEMM1)
    gemm_mfma<128, 128><<<gblk, 512, 0, stream>>>(h1, wc2, y2l, y2r, N);
    agg_head2<<<ablk, 256, 0, stream>>>(offs, cnt_i, csr, y2l, y2r, b2, Wlin, blin, outp, N);
}

// Round 6
// 213.766 us; speedup vs baseline: 3.8121x; 1.1688x over previous
//
#include <hip/hip_runtime.h>
#include <math.h>

#define F_IN 182
#define KP1  192   // padded K for layer 1
#define H1   128
#define H2   64

typedef short bf16x8 __attribute__((ext_vector_type(8)));
typedef float f32x4 __attribute__((ext_vector_type(4)));

__device__ __forceinline__ float b2f(short s) {
    unsigned u = ((unsigned)(unsigned short)s) << 16;
    return __builtin_bit_cast(float, u);
}
__device__ __forceinline__ short f2b(float f) {
    unsigned u = __builtin_bit_cast(unsigned, f);
    unsigned r = (u + 0x7FFFu + ((u >> 16) & 1u)) >> 16;
    return (short)(unsigned short)r;
}

#define GLOAD16(g, l) __builtin_amdgcn_global_load_lds( \
    (const __attribute__((address_space(1))) void*)(g), \
    (__attribute__((address_space(3))) void*)(l), 16, 0, 0)

// ---------------- fused: deg_count || conv_x || conv_w1 || conv_w2 ----------------
__global__ __launch_bounds__(256) void pre_fused(
    const int* __restrict__ dstv, int* __restrict__ cnt, int E, int degB,
    const float* __restrict__ x, short* __restrict__ xb, int nconvx, int cxB,
    const float* __restrict__ W1l, const float* __restrict__ W1r, short* __restrict__ wc1,
    const float* __restrict__ W2l, const float* __restrict__ W2r, short* __restrict__ wc2)
{
    int b = blockIdx.x, tid = threadIdx.x;
    if (b < degB) {
        // degree count: atomics without return value -> fire-and-forget
        int base = (b * 256 + tid) * 4;
        if (base + 4 <= E) {
            int4 d = *(const int4*)(dstv + base);
            atomicAdd(&cnt[d.x], 1); atomicAdd(&cnt[d.y], 1);
            atomicAdd(&cnt[d.z], 1); atomicAdd(&cnt[d.w], 1);
        } else {
            for (int e = base; e < E; ++e) atomicAdd(&cnt[dstv[e]], 1);
        }
        return;
    }
    b -= degB;
    if (b < cxB) {
        // x fp32 [N][182] -> bf16 [N][192]
        int idx = b * 256 + tid;
        if (idx < nconvx) {
            int row = idx / 24;
            int c8 = (idx - row * 24) * 8;
            const float* xr = x + (size_t)row * F_IN + c8;
            bf16x8 o;
            if (c8 + 8 <= F_IN) {
                float2 v0 = *(const float2*)(xr + 0);
                float2 v1 = *(const float2*)(xr + 2);
                float2 v2 = *(const float2*)(xr + 4);
                float2 v3 = *(const float2*)(xr + 6);
                o[0] = f2b(v0.x); o[1] = f2b(v0.y);
                o[2] = f2b(v1.x); o[3] = f2b(v1.y);
                o[4] = f2b(v2.x); o[5] = f2b(v2.y);
                o[6] = f2b(v3.x); o[7] = f2b(v3.y);
            } else {
#pragma unroll
                for (int i = 0; i < 8; ++i) {
                    int c = c8 + i;
                    o[i] = (c < F_IN) ? f2b(xr[i]) : (short)0;
                }
            }
            *(bf16x8*)(xb + (size_t)row * KP1 + c8) = o;
        }
        return;
    }
    b -= cxB;
    if (b < 192) {
        // W1 concat + pad -> bf16 [256][192]
        int idx = b * 256 + tid;
        int r = idx / KP1, k = idx - r * KP1;
        float v = 0.f;
        if (k < F_IN) v = (r < 128) ? W1l[r * F_IN + k] : W1r[(r - 128) * F_IN + k];
        wc1[idx] = f2b(v);
        return;
    }
    b -= 192;
    {
        // W2 concat -> bf16 [128][128]
        int idx = b * 256 + tid;
        int r = idx >> 7, k = idx & 127;
        float v = (r < 64) ? W2l[r * 128 + k] : W2r[(r - 64) * 128 + k];
        wc2[idx] = f2b(v);
    }
}

// ---------------- scans ----------------
__global__ __launch_bounds__(256) void scan_block(const int* __restrict__ in,
                                                  int* __restrict__ out,
                                                  int* __restrict__ bsums, int Nn) {
    __shared__ int s[256];
    int b = blockIdx.x, t = threadIdx.x;
    int base = b * 2048 + t * 8;
    int v[8]; int sum = 0;
#pragma unroll
    for (int i = 0; i < 8; ++i) { int idx = base + i; v[i] = (idx < Nn) ? in[idx] : 0; sum += v[i]; }
    s[t] = sum; __syncthreads();
    for (int off = 1; off < 256; off <<= 1) {
        int x = (t >= off) ? s[t - off] : 0; __syncthreads();
        s[t] += x; __syncthreads();
    }
    int excl = s[t] - sum;
    if (t == 255) bsums[b] = s[255];
    int run = excl;
#pragma unroll
    for (int i = 0; i < 8; ++i) { int idx = base + i; if (idx < Nn) out[idx] = run; run += v[i]; }
}

// single-wave exclusive scan over up to 64 block sums
__global__ __launch_bounds__(64) void scan_bsums(int* bs, int nb) {
    int l = threadIdx.x;
    int v = (l < nb) ? bs[l] : 0;
    int s = v;
#pragma unroll
    for (int off = 1; off < 64; off <<= 1) {
        int t = __shfl_up(s, off, 64);
        if (l >= off) s += t;
    }
    if (l < nb) bs[l] = s - v;
}

__global__ __launch_bounds__(256) void scan_add(int* __restrict__ offs,
                                                int* __restrict__ cursor,
                                                const int* __restrict__ bs, int Nn) {
    int i = blockIdx.x * 256 + threadIdx.x;
    if (i < Nn) { int o = offs[i] + bs[i >> 11]; offs[i] = o; cursor[i] = o; }
}

// ---------------- fused: csr_build || GEMM1 (y1 = xb @ [W1l;W1r]^T) ----------------
// csr blocks first (latency-bound, hidden under gemm compute), gemm blocks after.
// GEMM: BM=128, BK=64, 512 threads = 8 waves (2 row x 4 col), global_load_lds with
// XOR-swizzled LDS layout: lds_byte(row,col) = row*128 + (col ^ ((row&7)<<4)).
template <int NC, int KK, bool CSR>
__global__ __launch_bounds__(512) void gemm_mfma(
    const short* __restrict__ A, const short* __restrict__ W,
    short* __restrict__ outL, short* __restrict__ outR, int M,
    const int* __restrict__ srcv, const int* __restrict__ dstv,
    int* __restrict__ cursor, int* __restrict__ csr, int E, int csrB)
{
    constexpr int BM = 128, BK = 64;
    constexpr int WN = NC / 4;
    constexpr int NJ = WN / 16;
    constexpr int CA = BM / 64;
    constexpr int CB = NC / 64;
    __shared__ __attribute__((aligned(16))) short sA[BM * BK];
    __shared__ __attribute__((aligned(16))) short sB[NC * BK];
    int tid = threadIdx.x;
    if (CSR && (int)blockIdx.x < csrB) {
        int base = (blockIdx.x * 512 + tid) * 4;
        if (base + 4 <= E) {
            int4 d = *(const int4*)(dstv + base);
            int4 s = *(const int4*)(srcv + base);
            int p0 = atomicAdd(&cursor[d.x], 1);
            int p1 = atomicAdd(&cursor[d.y], 1);
            int p2 = atomicAdd(&cursor[d.z], 1);
            int p3 = atomicAdd(&cursor[d.w], 1);
            csr[p0] = s.x; csr[p1] = s.y; csr[p2] = s.z; csr[p3] = s.w;
        } else {
            for (int e = base; e < E; ++e) { int p = atomicAdd(&cursor[dstv[e]], 1); csr[p] = srcv[e]; }
        }
        return;
    }
    int bx = CSR ? ((int)blockIdx.x - csrB) : (int)blockIdx.x;
    int wid = tid >> 6, lane = tid & 63;
    int wr = wid >> 2, wc = wid & 3;
    int row0 = bx * BM;
    bool full = (row0 + BM <= M);
    const char* Ab = (const char*)A;
    const char* Wb = (const char*)W;
    f32x4 acc[4][NJ] = {};
    for (int k0 = 0; k0 < KK; k0 += BK) {
        if (full) {
#pragma unroll
            for (int c = 0; c < CA; ++c) {
                int idx = (wid * CA + c) * 64 + lane;
                int r = idx >> 3, cs = (idx & 7) * 16;
                const char* g = Ab + (size_t)(row0 + r) * (KK * 2) + k0 * 2 + (cs ^ ((r & 7) << 4));
                GLOAD16(g, (char*)sA + (size_t)(wid * CA + c) * 1024);
            }
#pragma unroll
            for (int c = 0; c < CB; ++c) {
                int idx = (wid * CB + c) * 64 + lane;
                int r = idx >> 3, cs = (idx & 7) * 16;
                const char* g = Wb + (size_t)r * (KK * 2) + k0 * 2 + (cs ^ ((r & 7) << 4));
                GLOAD16(g, (char*)sB + (size_t)(wid * CB + c) * 1024);
            }
        } else {
            for (int t = tid; t < BM * 8; t += 512) {
                int r = t >> 3, kc = (t & 7) * 16;
                bf16x8 v = {};
                int gr = row0 + r;
                if (gr < M) v = *(const bf16x8*)(Ab + (size_t)gr * (KK * 2) + k0 * 2 + kc);
                *(bf16x8*)((char*)sA + r * 128 + (kc ^ ((r & 7) << 4))) = v;
            }
            for (int t = tid; t < NC * 8; t += 512) {
                int r = t >> 3, kc = (t & 7) * 16;
                bf16x8 v = *(const bf16x8*)(Wb + (size_t)r * (KK * 2) + k0 * 2 + kc);
                *(bf16x8*)((char*)sB + r * 128 + (kc ^ ((r & 7) << 4))) = v;
            }
        }
        __syncthreads();
        int rl = lane & 15;
        int sw = (rl & 7) << 4;
#pragma unroll
        for (int ks = 0; ks < 2; ++ks) {
            int kb2 = ks * 64 + (lane >> 4) * 16;
            int cswz = kb2 ^ sw;
            bf16x8 af[4];
#pragma unroll
            for (int mi = 0; mi < 4; ++mi) {
                int row = wr * 64 + mi * 16 + rl;
                af[mi] = *(const bf16x8*)((const char*)sA + row * 128 + cswz);
            }
#pragma unroll
            for (int ni = 0; ni < NJ; ++ni) {
                int rowb = wc * WN + ni * 16 + rl;
                bf16x8 bfr = *(const bf16x8*)((const char*)sB + rowb * 128 + cswz);
#pragma unroll
                for (int mi = 0; mi < 4; ++mi)
                    acc[mi][ni] = __builtin_amdgcn_mfma_f32_16x16x32_bf16(af[mi], bfr, acc[mi][ni], 0, 0, 0);
            }
        }
        __syncthreads();
    }
    constexpr int HN = NC / 2;
#pragma unroll
    for (int mi = 0; mi < 4; ++mi) {
#pragma unroll
        for (int ni = 0; ni < NJ; ++ni) {
            int gc = wc * WN + ni * 16 + (lane & 15);
#pragma unroll
            for (int r = 0; r < 4; ++r) {
                int gr = row0 + wr * 64 + mi * 16 + (lane >> 4) * 4 + r;
                if (gr < M) {
                    short v = f2b(acc[mi][ni][r]);
                    if (gc < HN) outL[(size_t)gr * HN + gc] = v;
                    else         outR[(size_t)gr * HN + gc - HN] = v;
                }
            }
        }
    }
}

// ---------------- fused mean-aggregate + residual + bias + relu (layer 1) ----------------
__global__ __launch_bounds__(256) void agg_fuse1(const int* __restrict__ offs,
                                                 const int* __restrict__ degs,
                                                 const int* __restrict__ csr,
                                                 const short* __restrict__ yl,
                                                 const short* __restrict__ yr,
                                                 const float* __restrict__ bias,
                                                 short* __restrict__ h, int Nn) {
    int gid = blockIdx.x * 8 + (threadIdx.x >> 5);
    int l = threadIdx.x & 31;
    if (gid >= Nn) return;
    int start = offs[gid], deg = degs[gid];
    const size_t lo = (size_t)l * 4;
    float a0 = 0.f, a1 = 0.f, a2 = 0.f, a3 = 0.f;
    int t = 0;
    for (; t + 4 <= deg; t += 4) {
        int s0 = csr[start + t], s1 = csr[start + t + 1];
        int s2 = csr[start + t + 2], s3 = csr[start + t + 3];
        short4 v0 = *(const short4*)(yl + (size_t)s0 * H1 + lo);
        short4 v1 = *(const short4*)(yl + (size_t)s1 * H1 + lo);
        short4 v2 = *(const short4*)(yl + (size_t)s2 * H1 + lo);
        short4 v3 = *(const short4*)(yl + (size_t)s3 * H1 + lo);
        a0 += b2f(v0.x) + b2f(v1.x) + b2f(v2.x) + b2f(v3.x);
        a1 += b2f(v0.y) + b2f(v1.y) + b2f(v2.y) + b2f(v3.y);
        a2 += b2f(v0.z) + b2f(v1.z) + b2f(v2.z) + b2f(v3.z);
        a3 += b2f(v0.w) + b2f(v1.w) + b2f(v2.w) + b2f(v3.w);
    }
    for (; t < deg; ++t) {
        int s = csr[start + t];
        short4 v = *(const short4*)(yl + (size_t)s * H1 + lo);
        a0 += b2f(v.x); a1 += b2f(v.y); a2 += b2f(v.z); a3 += b2f(v.w);
    }
    float inv = 1.f / fmaxf((float)deg, 1.f);
    short4 rv = *(const short4*)(yr + (size_t)gid * H1 + lo);
    short4 o;
    o.x = f2b(fmaxf(a0 * inv + b2f(rv.x) + bias[l * 4 + 0], 0.f));
    o.y = f2b(fmaxf(a1 * inv + b2f(rv.y) + bias[l * 4 + 1], 0.f));
    o.z = f2b(fmaxf(a2 * inv + b2f(rv.z) + bias[l * 4 + 2], 0.f));
    o.w = f2b(fmaxf(a3 * inv + b2f(rv.w) + bias[l * 4 + 3], 0.f));
    *(short4*)(h + (size_t)gid * H1 + lo) = o;
}

// ------- fused mean-aggregate + residual + bias + relu + head + log_softmax (layer 2) -------
__global__ __launch_bounds__(256) void agg_head2(const int* __restrict__ offs,
                                                 const int* __restrict__ degs,
                                                 const int* __restrict__ csr,
                                                 const short* __restrict__ yl,
                                                 const short* __restrict__ yr,
                                                 const float* __restrict__ bias,
                                                 const float* __restrict__ Wlin,
                                                 const float* __restrict__ blin,
                                                 float* __restrict__ out, int Nn) {
    int gid = blockIdx.x * 8 + (threadIdx.x >> 5);
    int l = threadIdx.x & 31;
    if (gid >= Nn) return;
    int start = offs[gid], deg = degs[gid];
    const size_t lo = (size_t)l * 2;
    float a0 = 0.f, a1 = 0.f;
    int t = 0;
    for (; t + 4 <= deg; t += 4) {
        int s0 = csr[start + t], s1 = csr[start + t + 1];
        int s2 = csr[start + t + 2], s3 = csr[start + t + 3];
        short2 v0 = *(const short2*)(yl + (size_t)s0 * H2 + lo);
        short2 v1 = *(const short2*)(yl + (size_t)s1 * H2 + lo);
        short2 v2 = *(const short2*)(yl + (size_t)s2 * H2 + lo);
        short2 v3 = *(const short2*)(yl + (size_t)s3 * H2 + lo);
        a0 += b2f(v0.x) + b2f(v1.x) + b2f(v2.x) + b2f(v3.x);
        a1 += b2f(v0.y) + b2f(v1.y) + b2f(v2.y) + b2f(v3.y);
    }
    for (; t < deg; ++t) {
        int s = csr[start + t];
        short2 v = *(const short2*)(yl + (size_t)s * H2 + lo);
        a0 += b2f(v.x); a1 += b2f(v.y);
    }
    float inv = 1.f / fmaxf((float)deg, 1.f);
    short2 rv = *(const short2*)(yr + (size_t)gid * H2 + lo);
    float h0 = fmaxf(a0 * inv + b2f(rv.x) + bias[l * 2 + 0], 0.f);
    float h1v = fmaxf(a1 * inv + b2f(rv.y) + bias[l * 2 + 1], 0.f);
    float g0 = h0 * Wlin[2 * l] + h1v * Wlin[2 * l + 1];
    float g1 = h0 * Wlin[64 + 2 * l] + h1v * Wlin[64 + 2 * l + 1];
#pragma unroll
    for (int m = 16; m >= 1; m >>= 1) {
        g0 += __shfl_xor(g0, m, 32);
        g1 += __shfl_xor(g1, m, 32);
    }
    if (l == 0) {
        g0 += blin[0]; g1 += blin[1];
        float mx = fmaxf(g0, g1);
        float lse = mx + logf(expf(g0 - mx) + expf(g1 - mx));
        float2 r; r.x = g0 - lse; r.y = g1 - lse;
        ((float2*)out)[gid] = r;
    }
}

extern "C" void kernel_launch(void* const* d_in, const int* in_sizes, int n_in,
                              void* d_out, int out_size, void* d_ws, size_t ws_size,
                              hipStream_t stream) {
    const float* x    = (const float*)d_in[0];
    const int*   ei   = (const int*)d_in[1];
    const float* W1l  = (const float*)d_in[2];
    const float* W1r  = (const float*)d_in[3];
    const float* b1   = (const float*)d_in[4];
    const float* W2l  = (const float*)d_in[5];
    const float* W2r  = (const float*)d_in[6];
    const float* b2   = (const float*)d_in[7];
    const float* Wlin = (const float*)d_in[8];
    const float* blin = (const float*)d_in[9];
    float* outp = (float*)d_out;

    const int N = in_sizes[0] / F_IN;
    const int E = in_sizes[1] / 2;
    const int* srcv = ei;
    const int* dstv = ei + E;

    char* ws = (char*)d_ws;
    size_t o = 0;
    auto alloc = [&](size_t bytes) { size_t r = o; o += (bytes + 255) & ~(size_t)255; return r; };
    int* cnt_i  = (int*)(ws + alloc((size_t)N * 4));
    int* offs   = (int*)(ws + alloc((size_t)N * 4));
    int* cursor = (int*)(ws + alloc((size_t)N * 4));
    int* bsums  = (int*)(ws + alloc(1024));
    int* csr    = (int*)(ws + alloc((size_t)E * 4));
    short* xb   = (short*)(ws + alloc((size_t)N * KP1 * 2));
    short* wc1  = (short*)(ws + alloc((size_t)256 * KP1 * 2));
    short* wc2  = (short*)(ws + alloc((size_t)128 * 128 * 2));
    short* y1l  = (short*)(ws + alloc((size_t)N * H1 * 2));
    short* y1r  = (short*)(ws + alloc((size_t)N * H1 * 2));
    short* h1   = (short*)(ws + alloc((size_t)N * H1 * 2));
    // layer-2 buffers overlay xb (dead after GEMM1)
    short* y2l  = xb;
    short* y2r  = xb + (size_t)N * H2;

    const int degB = (E + 1023) / 1024;
    const int nconvx = N * 24;
    const int cxB  = (nconvx + 255) / 256;
    const int nb   = (N + 2047) / 2048;
    const int nthr = (N + 255) / 256;
    const int gblk = (N + 127) / 128;
    const int csrB = (E + 2047) / 2048;
    const int ablk = (N + 7) / 8;

    // zero degree counters, then fused preprocessing (deg || conv_x || conv_w1 || conv_w2)
    hipMemsetAsync(cnt_i, 0, (size_t)N * 4, stream);
    pre_fused<<<degB + cxB + 192 + 64, 256, 0, stream>>>(
        dstv, cnt_i, E, degB, x, xb, nconvx, cxB, W1l, W1r, wc1, W2l, W2r, wc2);

    // exclusive scan -> offsets, cursor
    scan_block<<<nb, 256, 0, stream>>>(cnt_i, offs, bsums, N);
    scan_bsums<<<1, 64, 0, stream>>>(bsums, nb);
    scan_add<<<nthr, 256, 0, stream>>>(offs, cursor, bsums, N);

    // fused: csr_build || GEMM1
    gemm_mfma<256, KP1, true><<<csrB + gblk, 512, 0, stream>>>(
        xb, wc1, y1l, y1r, N, srcv, dstv, cursor, csr, E, csrB);

    agg_fuse1<<<ablk, 256, 0, stream>>>(offs, cnt_i, csr, y1l, y1r, b1, h1, N);

    // layer 2 + head fused (y2 overlays xb, dead after GEMM1)
    gemm_mfma<128, 128, false><<<gblk, 512, 0, stream>>>(
        h1, wc2, y2l, y2r, N, nullptr, nullptr, nullptr, nullptr, 0, 0);
    agg_head2<<<ablk, 256, 0, stream>>>(offs, cnt_i, csr, y2l, y2r, b2, Wlin, blin, outp, N);
}

// Round 7
// 202.328 us; speedup vs baseline: 4.0276x; 1.0565x over previous
//
#include <hip/hip_runtime.h>
#include <math.h>

#define F_IN 182
#define H1   128
#define H2   64

typedef short bf16x8 __attribute__((ext_vector_type(8)));
typedef float f32x4 __attribute__((ext_vector_type(4)));

__device__ __forceinline__ float b2f(short s) {
    unsigned u = ((unsigned)(unsigned short)s) << 16;
    return __builtin_bit_cast(float, u);
}
__device__ __forceinline__ short f2b(float f) {
    unsigned u = __builtin_bit_cast(unsigned, f);
    unsigned r = (u + 0x7FFFu + ((u >> 16) & 1u)) >> 16;
    return (short)(unsigned short)r;
}

#define GLOAD16(g, l) __builtin_amdgcn_global_load_lds( \
    (const __attribute__((address_space(1))) void*)(g), \
    (__attribute__((address_space(3))) void*)(l), 16, 0, 0)

// ---------------- scans ----------------
__global__ __launch_bounds__(256) void scan_block(const int* __restrict__ in,
                                                  int* __restrict__ out,
                                                  int* __restrict__ bsums, int Nn) {
    __shared__ int s[256];
    int b = blockIdx.x, t = threadIdx.x;
    int base = b * 2048 + t * 8;
    int v[8]; int sum = 0;
#pragma unroll
    for (int i = 0; i < 8; ++i) { int idx = base + i; v[i] = (idx < Nn) ? in[idx] : 0; sum += v[i]; }
    s[t] = sum; __syncthreads();
    for (int off = 1; off < 256; off <<= 1) {
        int x = (t >= off) ? s[t - off] : 0; __syncthreads();
        s[t] += x; __syncthreads();
    }
    int excl = s[t] - sum;
    if (t == 255) bsums[b] = s[255];
    int run = excl;
#pragma unroll
    for (int i = 0; i < 8; ++i) { int idx = base + i; if (idx < Nn) out[idx] = run; run += v[i]; }
}

__global__ __launch_bounds__(64) void scan_bsums(int* bs, int nb) {
    int l = threadIdx.x;
    int v = (l < nb) ? bs[l] : 0;
    int s = v;
#pragma unroll
    for (int off = 1; off < 64; off <<= 1) {
        int t = __shfl_up(s, off, 64);
        if (l >= off) s += t;
    }
    if (l < nb) bs[l] = s - v;
}

__global__ __launch_bounds__(256) void scan_add(int* __restrict__ offs,
                                                const int* __restrict__ bs, int Nn) {
    int i = blockIdx.x * 256 + threadIdx.x;
    if (i < Nn) offs[i] += bs[i >> 11];
}

// ---------------- atomic-free CSR fill using precomputed ranks ----------------
__global__ __launch_bounds__(256) void csr_scatter(const int* __restrict__ srcv,
                                                   const int* __restrict__ dstv,
                                                   const int* __restrict__ rank,
                                                   const int* __restrict__ offs,
                                                   int* __restrict__ csr, int E) {
    int base = (blockIdx.x * 256 + threadIdx.x) * 4;
    if (base + 4 <= E) {
        int4 d = *(const int4*)(dstv + base);
        int4 s = *(const int4*)(srcv + base);
        int4 rk = *(const int4*)(rank + base);
        csr[offs[d.x] + rk.x] = s.x;
        csr[offs[d.y] + rk.y] = s.y;
        csr[offs[d.z] + rk.z] = s.z;
        csr[offs[d.w] + rk.w] = s.w;
    } else {
        for (int e = base; e < E; ++e) csr[offs[dstv[e]] + rank[e]] = srcv[e];
    }
}

// ---------------- fused: deg-rank (returning atomics) || bf16 MFMA GEMM ----------------
// GEMM: y = A @ [Wl;Wr]^T with fp32 W converted during staging.
// AF32: A is fp32 [M][KREAL], converted during staging (K zero-padded to KK).
// else: A is bf16 [M][KK] via global_load_lds.
// BM=128, BK=64, 512 threads = 8 waves (2 row x 4 col). XOR-swizzled LDS:
// lds_byte(row,col) = row*128 + (col ^ ((row&7)<<4)).
template <int NC, int KK, int KREAL, bool AF32, bool DEG>
__global__ __launch_bounds__(512) void gemm_fused(
    const void* __restrict__ Ap,
    const float* __restrict__ Wl, const float* __restrict__ Wr,
    short* __restrict__ outL, short* __restrict__ outR, int M,
    const int* __restrict__ dstv, int* __restrict__ cnt, int* __restrict__ rank,
    int E, int degB)
{
    constexpr int BM = 128, BK = 64;
    constexpr int WN = NC / 4;
    constexpr int NJ = WN / 16;
    __shared__ __attribute__((aligned(16))) short sA[BM * BK];
    __shared__ __attribute__((aligned(16))) short sB[NC * BK];
    int tid = threadIdx.x;

    if (DEG && (int)blockIdx.x < degB) {
        // degree count with returned rank (the single returning-atomic pass)
        int base = ((int)blockIdx.x * 512 + tid) * 4;
        if (base + 4 <= E) {
            int4 d = *(const int4*)(dstv + base);
            int4 rk;
            rk.x = atomicAdd(&cnt[d.x], 1);
            rk.y = atomicAdd(&cnt[d.y], 1);
            rk.z = atomicAdd(&cnt[d.z], 1);
            rk.w = atomicAdd(&cnt[d.w], 1);
            *(int4*)(rank + base) = rk;
        } else {
            for (int e = base; e < E; ++e) rank[e] = atomicAdd(&cnt[dstv[e]], 1);
        }
        return;
    }
    int bx = DEG ? ((int)blockIdx.x - degB) : (int)blockIdx.x;
    int wid = tid >> 6, lane = tid & 63;
    int wr = wid >> 2, wc = wid & 3;
    int row0 = bx * BM;
    bool full = (row0 + BM <= M);
    f32x4 acc[4][NJ] = {};
    for (int k0 = 0; k0 < KK; k0 += BK) {
        // ---- stage A ----
        if (AF32) {
            const float* Af = (const float*)Ap;
#pragma unroll
            for (int it = 0; it < 2; ++it) {
                int i = it * 512 + tid;
                int r = i >> 3, oct = i & 7;
                int gr = row0 + r;
                int gk = k0 + oct * 8;
                bf16x8 v = {};
                if (gr < M) {
                    const float* p = Af + (size_t)gr * KREAL + gk;
#pragma unroll
                    for (int j = 0; j < 4; ++j) {
                        if (gk + 2 * j + 2 <= KREAL) {
                            float2 f = *(const float2*)(p + 2 * j);
                            v[2 * j] = f2b(f.x); v[2 * j + 1] = f2b(f.y);
                        }
                    }
                }
                *(bf16x8*)((char*)sA + r * 128 + ((oct * 16) ^ ((r & 7) << 4))) = v;
            }
        } else {
            const char* Ab = (const char*)Ap;
            if (full) {
#pragma unroll
                for (int c = 0; c < 2; ++c) {
                    int idx = (wid * 2 + c) * 64 + lane;
                    int r = idx >> 3, cs = (idx & 7) * 16;
                    const char* g = Ab + (size_t)(row0 + r) * (KK * 2) + k0 * 2 + (cs ^ ((r & 7) << 4));
                    GLOAD16(g, (char*)sA + (size_t)(wid * 2 + c) * 1024);
                }
            } else {
                for (int t = tid; t < BM * 8; t += 512) {
                    int r = t >> 3, kc = (t & 7) * 16;
                    bf16x8 v = {};
                    int gr = row0 + r;
                    if (gr < M) v = *(const bf16x8*)(Ab + (size_t)gr * (KK * 2) + k0 * 2 + kc);
                    *(bf16x8*)((char*)sA + r * 128 + (kc ^ ((r & 7) << 4))) = v;
                }
            }
        }
        // ---- stage B (fp32 weights -> bf16) ----
        {
            constexpr int ITB = NC * 8 / 512;
#pragma unroll
            for (int it = 0; it < ITB; ++it) {
                int i = it * 512 + tid;
                int r = i >> 3, oct = i & 7;
                int gk = k0 + oct * 8;
                const float* wrow = (r < NC / 2) ? (Wl + (size_t)r * KREAL)
                                                 : (Wr + (size_t)(r - NC / 2) * KREAL);
                bf16x8 v = {};
                if constexpr (KREAL % 8 == 0) {
                    float4 f0 = *(const float4*)(wrow + gk);
                    float4 f1 = *(const float4*)(wrow + gk + 4);
                    v[0] = f2b(f0.x); v[1] = f2b(f0.y); v[2] = f2b(f0.z); v[3] = f2b(f0.w);
                    v[4] = f2b(f1.x); v[5] = f2b(f1.y); v[6] = f2b(f1.z); v[7] = f2b(f1.w);
                } else {
#pragma unroll
                    for (int j = 0; j < 4; ++j) {
                        if (gk + 2 * j + 2 <= KREAL) {
                            float2 f = *(const float2*)(wrow + gk + 2 * j);
                            v[2 * j] = f2b(f.x); v[2 * j + 1] = f2b(f.y);
                        }
                    }
                }
                *(bf16x8*)((char*)sB + r * 128 + ((oct * 16) ^ ((r & 7) << 4))) = v;
            }
        }
        __syncthreads();
        int rl = lane & 15;
        int sw = (rl & 7) << 4;
#pragma unroll
        for (int ks = 0; ks < 2; ++ks) {
            int kb2 = ks * 64 + (lane >> 4) * 16;
            int cswz = kb2 ^ sw;
            bf16x8 af[4];
#pragma unroll
            for (int mi = 0; mi < 4; ++mi) {
                int row = wr * 64 + mi * 16 + rl;
                af[mi] = *(const bf16x8*)((const char*)sA + row * 128 + cswz);
            }
#pragma unroll
            for (int ni = 0; ni < NJ; ++ni) {
                int rowb = wc * WN + ni * 16 + rl;
                bf16x8 bfr = *(const bf16x8*)((const char*)sB + rowb * 128 + cswz);
#pragma unroll
                for (int mi = 0; mi < 4; ++mi)
                    acc[mi][ni] = __builtin_amdgcn_mfma_f32_16x16x32_bf16(af[mi], bfr, acc[mi][ni], 0, 0, 0);
            }
        }
        __syncthreads();
    }
    constexpr int HN = NC / 2;
#pragma unroll
    for (int mi = 0; mi < 4; ++mi) {
#pragma unroll
        for (int ni = 0; ni < NJ; ++ni) {
            int gc = wc * WN + ni * 16 + (lane & 15);
#pragma unroll
            for (int r = 0; r < 4; ++r) {
                int gr = row0 + wr * 64 + mi * 16 + (lane >> 4) * 4 + r;
                if (gr < M) {
                    short v = f2b(acc[mi][ni][r]);
                    if (gc < HN) outL[(size_t)gr * HN + gc] = v;
                    else         outR[(size_t)gr * HN + gc - HN] = v;
                }
            }
        }
    }
}

// ---------------- fused mean-aggregate + residual + bias + relu (layer 1) ----------------
__global__ __launch_bounds__(256) void agg_fuse1(const int* __restrict__ offs,
                                                 const int* __restrict__ degs,
                                                 const int* __restrict__ csr,
                                                 const short* __restrict__ yl,
                                                 const short* __restrict__ yr,
                                                 const float* __restrict__ bias,
                                                 short* __restrict__ h, int Nn) {
    int gid = blockIdx.x * 8 + (threadIdx.x >> 5);
    int l = threadIdx.x & 31;
    if (gid >= Nn) return;
    int start = offs[gid], deg = degs[gid];
    const size_t lo = (size_t)l * 4;
    float a0 = 0.f, a1 = 0.f, a2 = 0.f, a3 = 0.f;
    int t = 0;
    for (; t + 4 <= deg; t += 4) {
        int s0 = csr[start + t], s1 = csr[start + t + 1];
        int s2 = csr[start + t + 2], s3 = csr[start + t + 3];
        short4 v0 = *(const short4*)(yl + (size_t)s0 * H1 + lo);
        short4 v1 = *(const short4*)(yl + (size_t)s1 * H1 + lo);
        short4 v2 = *(const short4*)(yl + (size_t)s2 * H1 + lo);
        short4 v3 = *(const short4*)(yl + (size_t)s3 * H1 + lo);
        a0 += b2f(v0.x) + b2f(v1.x) + b2f(v2.x) + b2f(v3.x);
        a1 += b2f(v0.y) + b2f(v1.y) + b2f(v2.y) + b2f(v3.y);
        a2 += b2f(v0.z) + b2f(v1.z) + b2f(v2.z) + b2f(v3.z);
        a3 += b2f(v0.w) + b2f(v1.w) + b2f(v2.w) + b2f(v3.w);
    }
    for (; t < deg; ++t) {
        int s = csr[start + t];
        short4 v = *(const short4*)(yl + (size_t)s * H1 + lo);
        a0 += b2f(v.x); a1 += b2f(v.y); a2 += b2f(v.z); a3 += b2f(v.w);
    }
    float inv = 1.f / fmaxf((float)deg, 1.f);
    short4 rv = *(const short4*)(yr + (size_t)gid * H1 + lo);
    short4 o;
    o.x = f2b(fmaxf(a0 * inv + b2f(rv.x) + bias[l * 4 + 0], 0.f));
    o.y = f2b(fmaxf(a1 * inv + b2f(rv.y) + bias[l * 4 + 1], 0.f));
    o.z = f2b(fmaxf(a2 * inv + b2f(rv.z) + bias[l * 4 + 2], 0.f));
    o.w = f2b(fmaxf(a3 * inv + b2f(rv.w) + bias[l * 4 + 3], 0.f));
    *(short4*)(h + (size_t)gid * H1 + lo) = o;
}

// ------- fused mean-aggregate + residual + bias + relu + head + log_softmax (layer 2) -------
__global__ __launch_bounds__(256) void agg_head2(const int* __restrict__ offs,
                                                 const int* __restrict__ degs,
                                                 const int* __restrict__ csr,
                                                 const short* __restrict__ yl,
                                                 const short* __restrict__ yr,
                                                 const float* __restrict__ bias,
                                                 const float* __restrict__ Wlin,
                                                 const float* __restrict__ blin,
                                                 float* __restrict__ out, int Nn) {
    int gid = blockIdx.x * 8 + (threadIdx.x >> 5);
    int l = threadIdx.x & 31;
    if (gid >= Nn) return;
    int start = offs[gid], deg = degs[gid];
    const size_t lo = (size_t)l * 2;
    float a0 = 0.f, a1 = 0.f;
    int t = 0;
    for (; t + 4 <= deg; t += 4) {
        int s0 = csr[start + t], s1 = csr[start + t + 1];
        int s2 = csr[start + t + 2], s3 = csr[start + t + 3];
        short2 v0 = *(const short2*)(yl + (size_t)s0 * H2 + lo);
        short2 v1 = *(const short2*)(yl + (size_t)s1 * H2 + lo);
        short2 v2 = *(const short2*)(yl + (size_t)s2 * H2 + lo);
        short2 v3 = *(const short2*)(yl + (size_t)s3 * H2 + lo);
        a0 += b2f(v0.x) + b2f(v1.x) + b2f(v2.x) + b2f(v3.x);
        a1 += b2f(v0.y) + b2f(v1.y) + b2f(v2.y) + b2f(v3.y);
    }
    for (; t < deg; ++t) {
        int s = csr[start + t];
        short2 v = *(const short2*)(yl + (size_t)s * H2 + lo);
        a0 += b2f(v.x); a1 += b2f(v.y);
    }
    float inv = 1.f / fmaxf((float)deg, 1.f);
    short2 rv = *(const short2*)(yr + (size_t)gid * H2 + lo);
    float h0 = fmaxf(a0 * inv + b2f(rv.x) + bias[l * 2 + 0], 0.f);
    float h1v = fmaxf(a1 * inv + b2f(rv.y) + bias[l * 2 + 1], 0.f);
    float g0 = h0 * Wlin[2 * l] + h1v * Wlin[2 * l + 1];
    float g1 = h0 * Wlin[64 + 2 * l] + h1v * Wlin[64 + 2 * l + 1];
#pragma unroll
    for (int m = 16; m >= 1; m >>= 1) {
        g0 += __shfl_xor(g0, m, 32);
        g1 += __shfl_xor(g1, m, 32);
    }
    if (l == 0) {
        g0 += blin[0]; g1 += blin[1];
        float mx = fmaxf(g0, g1);
        float lse = mx + logf(expf(g0 - mx) + expf(g1 - mx));
        float2 r; r.x = g0 - lse; r.y = g1 - lse;
        ((float2*)out)[gid] = r;
    }
}

extern "C" void kernel_launch(void* const* d_in, const int* in_sizes, int n_in,
                              void* d_out, int out_size, void* d_ws, size_t ws_size,
                              hipStream_t stream) {
    const float* x    = (const float*)d_in[0];
    const int*   ei   = (const int*)d_in[1];
    const float* W1l  = (const float*)d_in[2];
    const float* W1r  = (const float*)d_in[3];
    const float* b1   = (const float*)d_in[4];
    const float* W2l  = (const float*)d_in[5];
    const float* W2r  = (const float*)d_in[6];
    const float* b2   = (const float*)d_in[7];
    const float* Wlin = (const float*)d_in[8];
    const float* blin = (const float*)d_in[9];
    float* outp = (float*)d_out;

    const int N = in_sizes[0] / F_IN;
    const int E = in_sizes[1] / 2;
    const int* srcv = ei;
    const int* dstv = ei + E;

    char* ws = (char*)d_ws;
    size_t o = 0;
    auto alloc = [&](size_t bytes) { size_t r = o; o += (bytes + 255) & ~(size_t)255; return r; };
    int* cnt_i  = (int*)(ws + alloc((size_t)N * 4));
    int* offs   = (int*)(ws + alloc((size_t)N * 4));
    int* bsums  = (int*)(ws + alloc(1024));
    int* rank   = (int*)(ws + alloc((size_t)E * 4));
    int* csr    = (int*)(ws + alloc((size_t)E * 4));
    short* y1l  = (short*)(ws + alloc((size_t)N * H1 * 2));
    short* y1r  = (short*)(ws + alloc((size_t)N * H1 * 2));
    short* h1   = (short*)(ws + alloc((size_t)N * H1 * 2));
    // layer-2 outputs overlay y1 buffers (dead after agg_fuse1)
    short* y2l  = y1l;
    short* y2r  = y1r;

    const int degB = (E + 2047) / 2048;          // 512 thr x 4 edges
    const int nb   = (N + 2047) / 2048;
    const int nthr = (N + 255) / 256;
    const int gblk = (N + 127) / 128;
    const int e4   = (E + 1023) / 1024;          // 256 thr x 4 edges
    const int ablk = (N + 7) / 8;

    // zero degree counters
    hipMemsetAsync(cnt_i, 0, (size_t)N * 4, stream);

    // K1: deg-rank (returning atomics) || GEMM1 straight from fp32 x and fp32 W1
    gemm_fused<256, 192, F_IN, true, true><<<degB + gblk, 512, 0, stream>>>(
        x, W1l, W1r, y1l, y1r, N, dstv, cnt_i, rank, E, degB);

    // exclusive scan of degrees -> offs
    scan_block<<<nb, 256, 0, stream>>>(cnt_i, offs, bsums, N);
    scan_bsums<<<1, 64, 0, stream>>>(bsums, nb);
    scan_add<<<nthr, 256, 0, stream>>>(offs, bsums, N);

    // atomic-free CSR fill
    csr_scatter<<<e4, 256, 0, stream>>>(srcv, dstv, rank, offs, csr, E);

    // layer 1 aggregate + bias + relu
    agg_fuse1<<<ablk, 256, 0, stream>>>(offs, cnt_i, csr, y1l, y1r, b1, h1, N);

    // layer 2 GEMM (bf16 A = h1, fp32 W2 converted in-kernel)
    gemm_fused<128, 128, 128, false, false><<<gblk, 512, 0, stream>>>(
        h1, W2l, W2r, y2l, y2r, N, nullptr, nullptr, nullptr, 0, 0);

    // layer 2 aggregate + head + log_softmax
    agg_head2<<<ablk, 256, 0, stream>>>(offs, cnt_i, csr, y2l, y2r, b2, Wlin, blin, outp, N);
}

// Round 8
// 171.150 us; speedup vs baseline: 4.7613x; 1.1822x over previous
//
#include <hip/hip_runtime.h>
#include <math.h>

#define F_IN 182
#define H1   128
#define H2   64

typedef short bf16x8 __attribute__((ext_vector_type(8)));
typedef float f32x4 __attribute__((ext_vector_type(4)));

__device__ __forceinline__ float b2f(short s) {
    unsigned u = ((unsigned)(unsigned short)s) << 16;
    return __builtin_bit_cast(float, u);
}
__device__ __forceinline__ short f2b(float f) {
    unsigned u = __builtin_bit_cast(unsigned, f);
    unsigned r = (u + 0x7FFFu + ((u >> 16) & 1u)) >> 16;
    return (short)(unsigned short)r;
}

#define GLOAD16(g, l) __builtin_amdgcn_global_load_lds( \
    (const __attribute__((address_space(1))) void*)(g), \
    (__attribute__((address_space(3))) void*)(l), 16, 0, 0)

// ---------------- prelude: zero cnt || conv W1 -> bf16 [256][192] || W2 -> bf16 [128][128] ----
__global__ __launch_bounds__(256) void prelude(
    int* __restrict__ cnt, int Nn, int zB,
    const float* __restrict__ W1l, const float* __restrict__ W1r, short* __restrict__ wc1,
    const float* __restrict__ W2l, const float* __restrict__ W2r, short* __restrict__ wc2)
{
    int b = blockIdx.x, tid = threadIdx.x;
    if (b < zB) {
        int i = (b * 256 + tid) * 4;
        if (i + 4 <= Nn) {
            int4 z = make_int4(0, 0, 0, 0);
            *(int4*)(cnt + i) = z;
        } else {
            for (int j = i; j < Nn; ++j) cnt[j] = 0;
        }
        return;
    }
    b -= zB;
    if (b < 192) {
        // wc1: [256][192], rows 0-127 = W1l, 128-255 = W1r, cols >= 182 zero
        int idx = b * 256 + tid;
        int r = idx / 192, k = idx - r * 192;
        float v = 0.f;
        if (k < F_IN) v = (r < 128) ? W1l[r * F_IN + k] : W1r[(r - 128) * F_IN + k];
        wc1[idx] = f2b(v);
        return;
    }
    b -= 192;
    {
        // wc2: [128][128], rows 0-63 = W2l, 64-127 = W2r
        int idx = b * 256 + tid;
        int r = idx >> 7, k = idx & 127;
        float v = (r < 64) ? W2l[r * 128 + k] : W2r[(r - 64) * 128 + k];
        wc2[idx] = f2b(v);
    }
}

// ---------------- scans ----------------
__global__ __launch_bounds__(256) void scan_block(const int* __restrict__ in,
                                                  int* __restrict__ out,
                                                  int* __restrict__ bsums, int Nn) {
    __shared__ int s[256];
    int b = blockIdx.x, t = threadIdx.x;
    int base = b * 2048 + t * 8;
    int v[8]; int sum = 0;
#pragma unroll
    for (int i = 0; i < 8; ++i) { int idx = base + i; v[i] = (idx < Nn) ? in[idx] : 0; sum += v[i]; }
    s[t] = sum; __syncthreads();
    for (int off = 1; off < 256; off <<= 1) {
        int x = (t >= off) ? s[t - off] : 0; __syncthreads();
        s[t] += x; __syncthreads();
    }
    int excl = s[t] - sum;
    if (t == 255) bsums[b] = s[255];
    int run = excl;
#pragma unroll
    for (int i = 0; i < 8; ++i) { int idx = base + i; if (idx < Nn) out[idx] = run; run += v[i]; }
}

__global__ __launch_bounds__(64) void scan_bsums(int* bs, int nb) {
    int l = threadIdx.x;
    int v = (l < nb) ? bs[l] : 0;
    int s = v;
#pragma unroll
    for (int off = 1; off < 64; off <<= 1) {
        int t = __shfl_up(s, off, 64);
        if (l >= off) s += t;
    }
    if (l < nb) bs[l] = s - v;
}

__global__ __launch_bounds__(256) void scan_add(int* __restrict__ offs,
                                                const int* __restrict__ bs, int Nn) {
    int i = blockIdx.x * 256 + threadIdx.x;
    if (i < Nn) offs[i] += bs[i >> 11];
}

// ---------------- atomic-free CSR fill using precomputed ranks ----------------
__global__ __launch_bounds__(256) void csr_scatter(const int* __restrict__ srcv,
                                                   const int* __restrict__ dstv,
                                                   const int* __restrict__ rank,
                                                   const int* __restrict__ offs,
                                                   int* __restrict__ csr, int E) {
    int base = (blockIdx.x * 256 + threadIdx.x) * 4;
    if (base + 4 <= E) {
        int4 d = *(const int4*)(dstv + base);
        int4 s = *(const int4*)(srcv + base);
        int4 rk = *(const int4*)(rank + base);
        csr[offs[d.x] + rk.x] = s.x;
        csr[offs[d.y] + rk.y] = s.y;
        csr[offs[d.z] + rk.z] = s.z;
        csr[offs[d.w] + rk.w] = s.w;
    } else {
        for (int e = base; e < E; ++e) csr[offs[dstv[e]] + rank[e]] = srcv[e];
    }
}

// ---------------- fused: deg-rank (returning atomics) || bf16 MFMA GEMM ----------------
// y = A @ Wcat^T. Wcat: precomputed bf16 [NC][KK] (always gload16-staged).
// AF32: A is fp32 [M][KREAL] converted during staging (K zero-padded to KK);
// else: A is bf16 [M][KK] via global_load_lds.
// BM=128, BK=64, 512 threads = 8 waves (2 row x 4 col). XOR-swizzled LDS:
// lds_byte(row,col) = row*128 + (col ^ ((row&7)<<4)).
template <int NC, int KK, int KREAL, bool AF32, bool DEG>
__global__ __launch_bounds__(512) void gemm_fused(
    const void* __restrict__ Ap, const short* __restrict__ Wcat,
    short* __restrict__ outL, short* __restrict__ outR, int M,
    const int* __restrict__ dstv, int* __restrict__ cnt, int* __restrict__ rank,
    int E, int degB)
{
    constexpr int BM = 128, BK = 64;
    constexpr int WN = NC / 4;
    constexpr int NJ = WN / 16;
    constexpr int CB = NC * 8 / 512;   // B gload items per thread-slot
    __shared__ __attribute__((aligned(16))) short sA[BM * BK];
    __shared__ __attribute__((aligned(16))) short sB[NC * BK];
    int tid = threadIdx.x;

    if (DEG && (int)blockIdx.x < degB) {
        // degree count with returned rank: the single returning-atomic pass
        int base = ((int)blockIdx.x * 512 + tid) * 4;
        if (base + 4 <= E) {
            int4 d = *(const int4*)(dstv + base);
            int4 rk;
            rk.x = atomicAdd(&cnt[d.x], 1);
            rk.y = atomicAdd(&cnt[d.y], 1);
            rk.z = atomicAdd(&cnt[d.z], 1);
            rk.w = atomicAdd(&cnt[d.w], 1);
            *(int4*)(rank + base) = rk;
        } else {
            for (int e = base; e < E; ++e) rank[e] = atomicAdd(&cnt[dstv[e]], 1);
        }
        return;
    }
    int bx = DEG ? ((int)blockIdx.x - degB) : (int)blockIdx.x;
    int wid = tid >> 6, lane = tid & 63;
    int wr = wid >> 2, wc = wid & 3;
    int row0 = bx * BM;
    bool full = (row0 + BM <= M);
    f32x4 acc[4][NJ] = {};
#pragma unroll
    for (int ksi = 0; ksi < KK / BK; ++ksi) {
        const int k0 = ksi * BK;
        // ---- stage A ----
        if (AF32) {
            const float* Af = (const float*)Ap;
#pragma unroll
            for (int it = 0; it < 2; ++it) {
                int i = it * 512 + tid;
                int r = i >> 3, oct = i & 7;
                int gr = row0 + r;
                int gk = k0 + oct * 8;
                bf16x8 v = {};
                if (gr < M) {
                    const float* p = Af + (size_t)gr * KREAL + gk;
                    if (k0 + BK <= KREAL) {   // compile-time after unroll: steps 0,1
                        float2 f0 = *(const float2*)(p + 0);
                        float2 f1 = *(const float2*)(p + 2);
                        float2 f2 = *(const float2*)(p + 4);
                        float2 f3 = *(const float2*)(p + 6);
                        v[0] = f2b(f0.x); v[1] = f2b(f0.y);
                        v[2] = f2b(f1.x); v[3] = f2b(f1.y);
                        v[4] = f2b(f2.x); v[5] = f2b(f2.y);
                        v[6] = f2b(f3.x); v[7] = f2b(f3.y);
                    } else {                  // tail K step: per-pair validity
#pragma unroll
                        for (int j = 0; j < 4; ++j) {
                            if (gk + 2 * j + 2 <= KREAL) {
                                float2 f = *(const float2*)(p + 2 * j);
                                v[2 * j] = f2b(f.x); v[2 * j + 1] = f2b(f.y);
                            }
                        }
                    }
                }
                *(bf16x8*)((char*)sA + r * 128 + ((oct * 16) ^ ((r & 7) << 4))) = v;
            }
        } else {
            const char* Ab = (const char*)Ap;
            if (full) {
#pragma unroll
                for (int c = 0; c < 2; ++c) {
                    int idx = (wid * 2 + c) * 64 + lane;
                    int r = idx >> 3, cs = (idx & 7) * 16;
                    const char* g = Ab + (size_t)(row0 + r) * (KK * 2) + k0 * 2 + (cs ^ ((r & 7) << 4));
                    GLOAD16(g, (char*)sA + (size_t)(wid * 2 + c) * 1024);
                }
            } else {
                for (int t = tid; t < BM * 8; t += 512) {
                    int r = t >> 3, kc = (t & 7) * 16;
                    bf16x8 v = {};
                    int gr = row0 + r;
                    if (gr < M) v = *(const bf16x8*)(Ab + (size_t)gr * (KK * 2) + k0 * 2 + kc);
                    *(bf16x8*)((char*)sA + r * 128 + (kc ^ ((r & 7) << 4))) = v;
                }
            }
        }
        // ---- stage B: precomputed bf16 weights via global_load_lds ----
#pragma unroll
        for (int c = 0; c < CB; ++c) {
            int idx = (wid * CB + c) * 64 + lane;
            int r = idx >> 3, cs = (idx & 7) * 16;
            const char* g = (const char*)Wcat + (size_t)r * (KK * 2) + k0 * 2 + (cs ^ ((r & 7) << 4));
            GLOAD16(g, (char*)sB + (size_t)(wid * CB + c) * 1024);
        }
        __syncthreads();
        int rl = lane & 15;
        int sw = (rl & 7) << 4;
#pragma unroll
        for (int ks = 0; ks < 2; ++ks) {
            int kb2 = ks * 64 + (lane >> 4) * 16;
            int cswz = kb2 ^ sw;
            bf16x8 af[4];
#pragma unroll
            for (int mi = 0; mi < 4; ++mi) {
                int row = wr * 64 + mi * 16 + rl;
                af[mi] = *(const bf16x8*)((const char*)sA + row * 128 + cswz);
            }
#pragma unroll
            for (int ni = 0; ni < NJ; ++ni) {
                int rowb = wc * WN + ni * 16 + rl;
                bf16x8 bfr = *(const bf16x8*)((const char*)sB + rowb * 128 + cswz);
#pragma unroll
                for (int mi = 0; mi < 4; ++mi)
                    acc[mi][ni] = __builtin_amdgcn_mfma_f32_16x16x32_bf16(af[mi], bfr, acc[mi][ni], 0, 0, 0);
            }
        }
        __syncthreads();
    }
    constexpr int HN = NC / 2;
#pragma unroll
    for (int mi = 0; mi < 4; ++mi) {
#pragma unroll
        for (int ni = 0; ni < NJ; ++ni) {
            int gc = wc * WN + ni * 16 + (lane & 15);
#pragma unroll
            for (int r = 0; r < 4; ++r) {
                int gr = row0 + wr * 64 + mi * 16 + (lane >> 4) * 4 + r;
                if (gr < M) {
                    short v = f2b(acc[mi][ni][r]);
                    if (gc < HN) outL[(size_t)gr * HN + gc] = v;
                    else         outR[(size_t)gr * HN + gc - HN] = v;
                }
            }
        }
    }
}

// ------- fused mean-aggregate + residual + bias + relu (layer 1): 16 lanes/node, 16B loads ----
__global__ __launch_bounds__(256) void agg_fuse1(const int* __restrict__ offs,
                                                 const int* __restrict__ degs,
                                                 const int* __restrict__ csr,
                                                 const short* __restrict__ yl,
                                                 const short* __restrict__ yr,
                                                 const float* __restrict__ bias,
                                                 short* __restrict__ h, int Nn) {
    int gid = blockIdx.x * 16 + (threadIdx.x >> 4);
    int l = threadIdx.x & 15;
    if (gid >= Nn) return;
    int start = offs[gid], deg = degs[gid];
    const int co = l * 8;
    float a[8] = {};
    int t = 0;
    for (; t + 4 <= deg; t += 4) {
        int s0 = csr[start + t], s1 = csr[start + t + 1];
        int s2 = csr[start + t + 2], s3 = csr[start + t + 3];
        bf16x8 v0 = *(const bf16x8*)(yl + (size_t)s0 * H1 + co);
        bf16x8 v1 = *(const bf16x8*)(yl + (size_t)s1 * H1 + co);
        bf16x8 v2 = *(const bf16x8*)(yl + (size_t)s2 * H1 + co);
        bf16x8 v3 = *(const bf16x8*)(yl + (size_t)s3 * H1 + co);
#pragma unroll
        for (int j = 0; j < 8; ++j)
            a[j] += b2f(v0[j]) + b2f(v1[j]) + b2f(v2[j]) + b2f(v3[j]);
    }
    for (; t < deg; ++t) {
        int s = csr[start + t];
        bf16x8 v = *(const bf16x8*)(yl + (size_t)s * H1 + co);
#pragma unroll
        for (int j = 0; j < 8; ++j) a[j] += b2f(v[j]);
    }
    float inv = 1.f / fmaxf((float)deg, 1.f);
    bf16x8 rv = *(const bf16x8*)(yr + (size_t)gid * H1 + co);
    bf16x8 o;
#pragma unroll
    for (int j = 0; j < 8; ++j)
        o[j] = f2b(fmaxf(a[j] * inv + b2f(rv[j]) + bias[co + j], 0.f));
    *(bf16x8*)(h + (size_t)gid * H1 + co) = o;
}

// ------- fused agg + residual + bias + relu + head + log_softmax (layer 2): 16 lanes/node ----
__global__ __launch_bounds__(256) void agg_head2(const int* __restrict__ offs,
                                                 const int* __restrict__ degs,
                                                 const int* __restrict__ csr,
                                                 const short* __restrict__ yl,
                                                 const short* __restrict__ yr,
                                                 const float* __restrict__ bias,
                                                 const float* __restrict__ Wlin,
                                                 const float* __restrict__ blin,
                                                 float* __restrict__ out, int Nn) {
    int gid = blockIdx.x * 16 + (threadIdx.x >> 4);
    int l = threadIdx.x & 15;
    if (gid >= Nn) return;
    int start = offs[gid], deg = degs[gid];
    const int co = l * 4;
    float a[4] = {};
    int t = 0;
    for (; t + 4 <= deg; t += 4) {
        int s0 = csr[start + t], s1 = csr[start + t + 1];
        int s2 = csr[start + t + 2], s3 = csr[start + t + 3];
        short4 v0 = *(const short4*)(yl + (size_t)s0 * H2 + co);
        short4 v1 = *(const short4*)(yl + (size_t)s1 * H2 + co);
        short4 v2 = *(const short4*)(yl + (size_t)s2 * H2 + co);
        short4 v3 = *(const short4*)(yl + (size_t)s3 * H2 + co);
        a[0] += b2f(v0.x) + b2f(v1.x) + b2f(v2.x) + b2f(v3.x);
        a[1] += b2f(v0.y) + b2f(v1.y) + b2f(v2.y) + b2f(v3.y);
        a[2] += b2f(v0.z) + b2f(v1.z) + b2f(v2.z) + b2f(v3.z);
        a[3] += b2f(v0.w) + b2f(v1.w) + b2f(v2.w) + b2f(v3.w);
    }
    for (; t < deg; ++t) {
        int s = csr[start + t];
        short4 v = *(const short4*)(yl + (size_t)s * H2 + co);
        a[0] += b2f(v.x); a[1] += b2f(v.y); a[2] += b2f(v.z); a[3] += b2f(v.w);
    }
    float inv = 1.f / fmaxf((float)deg, 1.f);
    short4 rv = *(const short4*)(yr + (size_t)gid * H2 + co);
    float h0 = fmaxf(a[0] * inv + b2f(rv.x) + bias[co + 0], 0.f);
    float h1v = fmaxf(a[1] * inv + b2f(rv.y) + bias[co + 1], 0.f);
    float h2v = fmaxf(a[2] * inv + b2f(rv.z) + bias[co + 2], 0.f);
    float h3v = fmaxf(a[3] * inv + b2f(rv.w) + bias[co + 3], 0.f);
    float g0 = h0 * Wlin[co] + h1v * Wlin[co + 1] + h2v * Wlin[co + 2] + h3v * Wlin[co + 3];
    float g1 = h0 * Wlin[64 + co] + h1v * Wlin[64 + co + 1] + h2v * Wlin[64 + co + 2] + h3v * Wlin[64 + co + 3];
#pragma unroll
    for (int m = 8; m >= 1; m >>= 1) {
        g0 += __shfl_xor(g0, m, 16);
        g1 += __shfl_xor(g1, m, 16);
    }
    if (l == 0) {
        g0 += blin[0]; g1 += blin[1];
        float mx = fmaxf(g0, g1);
        float lse = mx + logf(expf(g0 - mx) + expf(g1 - mx));
        float2 r; r.x = g0 - lse; r.y = g1 - lse;
        ((float2*)out)[gid] = r;
    }
}

extern "C" void kernel_launch(void* const* d_in, const int* in_sizes, int n_in,
                              void* d_out, int out_size, void* d_ws, size_t ws_size,
                              hipStream_t stream) {
    const float* x    = (const float*)d_in[0];
    const int*   ei   = (const int*)d_in[1];
    const float* W1l  = (const float*)d_in[2];
    const float* W1r  = (const float*)d_in[3];
    const float* b1   = (const float*)d_in[4];
    const float* W2l  = (const float*)d_in[5];
    const float* W2r  = (const float*)d_in[6];
    const float* b2   = (const float*)d_in[7];
    const float* Wlin = (const float*)d_in[8];
    const float* blin = (const float*)d_in[9];
    float* outp = (float*)d_out;

    const int N = in_sizes[0] / F_IN;
    const int E = in_sizes[1] / 2;
    const int* srcv = ei;
    const int* dstv = ei + E;

    char* ws = (char*)d_ws;
    size_t o = 0;
    auto alloc = [&](size_t bytes) { size_t r = o; o += (bytes + 255) & ~(size_t)255; return r; };
    int* cnt_i  = (int*)(ws + alloc((size_t)N * 4));
    int* offs   = (int*)(ws + alloc((size_t)N * 4));
    int* bsums  = (int*)(ws + alloc(1024));
    int* rank   = (int*)(ws + alloc((size_t)E * 4));
    int* csr    = (int*)(ws + alloc((size_t)E * 4));
    short* wc1  = (short*)(ws + alloc((size_t)256 * 192 * 2));
    short* wc2  = (short*)(ws + alloc((size_t)128 * 128 * 2));
    short* y1l  = (short*)(ws + alloc((size_t)N * H1 * 2));
    short* y1r  = (short*)(ws + alloc((size_t)N * H1 * 2));
    short* h1   = (short*)(ws + alloc((size_t)N * H1 * 2));
    // layer-2 outputs overlay y1 buffers (dead after agg_fuse1)
    short* y2l  = y1l;
    short* y2r  = y1r;

    const int zB   = (N + 1023) / 1024;
    const int degB = (E + 2047) / 2048;          // 512 thr x 4 edges
    const int nb   = (N + 2047) / 2048;
    const int nthr = (N + 255) / 256;
    const int gblk = (N + 127) / 128;
    const int e4   = (E + 1023) / 1024;          // 256 thr x 4 edges
    const int a16  = (N + 15) / 16;

    // prelude: zero cnt || build bf16 weight buffers
    prelude<<<zB + 192 + 64, 256, 0, stream>>>(cnt_i, N, zB, W1l, W1r, wc1, W2l, W2r, wc2);

    // K1: deg-rank (returning atomics) || GEMM1 from fp32 x and bf16 wc1
    gemm_fused<256, 192, F_IN, true, true><<<degB + gblk, 512, 0, stream>>>(
        x, wc1, y1l, y1r, N, dstv, cnt_i, rank, E, degB);

    // exclusive scan of degrees -> offs
    scan_block<<<nb, 256, 0, stream>>>(cnt_i, offs, bsums, N);
    scan_bsums<<<1, 64, 0, stream>>>(bsums, nb);
    scan_add<<<nthr, 256, 0, stream>>>(offs, bsums, N);

    // atomic-free CSR fill
    csr_scatter<<<e4, 256, 0, stream>>>(srcv, dstv, rank, offs, csr, E);

    // layer 1 aggregate + bias + relu
    agg_fuse1<<<a16, 256, 0, stream>>>(offs, cnt_i, csr, y1l, y1r, b1, h1, N);

    // layer 2 GEMM (bf16 A = h1 via gload16, bf16 wc2 via gload16)
    gemm_fused<128, 128, 128, false, false><<<gblk, 512, 0, stream>>>(
        h1, wc2, y2l, y2r, N, nullptr, nullptr, nullptr, 0, 0);

    // layer 2 aggregate + head + log_softmax
    agg_head2<<<a16, 256, 0, stream>>>(offs, cnt_i, csr, y2l, y2r, b2, Wlin, blin, outp, N);
}

// Round 10
// 169.617 us; speedup vs baseline: 4.8044x; 1.0090x over previous
//
#include <hip/hip_runtime.h>
#include <hip/hip_bf16.h>
#include <math.h>

#define F_IN 182
#define H1   128
#define H2   64

typedef short bf16x8 __attribute__((ext_vector_type(8)));
typedef float f32x4 __attribute__((ext_vector_type(4)));

__device__ __forceinline__ float b2f(short s) {
    unsigned u = ((unsigned)(unsigned short)s) << 16;
    return __builtin_bit_cast(float, u);
}
// hardware cvt — compiler lowers scalar casts (and fuses pairs into v_cvt_pk_bf16_f32)
__device__ __forceinline__ short f2b(float f) {
    return __builtin_bit_cast(short, __float2bfloat16(f));
}
__device__ __forceinline__ short2 f2x2(float2 f) {
    short2 r;
    r.x = f2b(f.x);
    r.y = f2b(f.y);
    return r;
}

#define GLOAD16(g, l) __builtin_amdgcn_global_load_lds( \
    (const __attribute__((address_space(1))) void*)(g), \
    (__attribute__((address_space(3))) void*)(l), 16, 0, 0)

// ---------------- prelude: zero cnt || conv W1 -> bf16 [256][192] || W2 -> bf16 [128][128] ----
__global__ __launch_bounds__(256) void prelude(
    int* __restrict__ cnt, int Nn, int zB,
    const float* __restrict__ W1l, const float* __restrict__ W1r, short* __restrict__ wc1,
    const float* __restrict__ W2l, const float* __restrict__ W2r, short* __restrict__ wc2)
{
    int b = blockIdx.x, tid = threadIdx.x;
    if (b < zB) {
        int i = (b * 256 + tid) * 4;
        if (i + 4 <= Nn) {
            int4 z = make_int4(0, 0, 0, 0);
            *(int4*)(cnt + i) = z;
        } else {
            for (int j = i; j < Nn; ++j) cnt[j] = 0;
        }
        return;
    }
    b -= zB;
    if (b < 192) {
        int idx = b * 256 + tid;
        int r = idx / 192, k = idx - r * 192;
        float v = 0.f;
        if (k < F_IN) v = (r < 128) ? W1l[r * F_IN + k] : W1r[(r - 128) * F_IN + k];
        wc1[idx] = f2b(v);
        return;
    }
    b -= 192;
    {
        int idx = b * 256 + tid;
        int r = idx >> 7, k = idx & 127;
        float v = (r < 64) ? W2l[r * 128 + k] : W2r[(r - 64) * 128 + k];
        wc2[idx] = f2b(v);
    }
}

// ---------------- scans ----------------
__global__ __launch_bounds__(256) void scan_block(const int* __restrict__ in,
                                                  int* __restrict__ out,
                                                  int* __restrict__ bsums, int Nn) {
    __shared__ int s[256];
    int b = blockIdx.x, t = threadIdx.x;
    int base = b * 2048 + t * 8;
    int v[8]; int sum = 0;
#pragma unroll
    for (int i = 0; i < 8; ++i) { int idx = base + i; v[i] = (idx < Nn) ? in[idx] : 0; sum += v[i]; }
    s[t] = sum; __syncthreads();
    for (int off = 1; off < 256; off <<= 1) {
        int x = (t >= off) ? s[t - off] : 0; __syncthreads();
        s[t] += x; __syncthreads();
    }
    int excl = s[t] - sum;
    if (t == 255) bsums[b] = s[255];
    int run = excl;
#pragma unroll
    for (int i = 0; i < 8; ++i) { int idx = base + i; if (idx < Nn) out[idx] = run; run += v[i]; }
}

// scan_add with inlined bsums exclusive scan (nb <= 64)
__global__ __launch_bounds__(256) void scan_add(int* __restrict__ offs,
                                                const int* __restrict__ bsums,
                                                int nb, int Nn) {
    __shared__ int sbs[64];
    int t = threadIdx.x;
    if (t < 64) {
        int v = (t < nb) ? bsums[t] : 0;
        int s = v;
#pragma unroll
        for (int off = 1; off < 64; off <<= 1) {
            int u = __shfl_up(s, off, 64);
            if (t >= off) s += u;
        }
        sbs[t] = s - v;
    }
    __syncthreads();
    int i = blockIdx.x * 256 + t;
    if (i < Nn) offs[i] += sbs[i >> 11];
}

// ---------------- atomic-free CSR fill using precomputed ranks ----------------
__global__ __launch_bounds__(256) void csr_scatter(const int* __restrict__ srcv,
                                                   const int* __restrict__ dstv,
                                                   const int* __restrict__ rank,
                                                   const int* __restrict__ offs,
                                                   int* __restrict__ csr, int E) {
    int base = (blockIdx.x * 256 + threadIdx.x) * 4;
    if (base + 4 <= E) {
        int4 d = *(const int4*)(dstv + base);
        int4 s = *(const int4*)(srcv + base);
        int4 rk = *(const int4*)(rank + base);
        csr[offs[d.x] + rk.x] = s.x;
        csr[offs[d.y] + rk.y] = s.y;
        csr[offs[d.z] + rk.z] = s.z;
        csr[offs[d.w] + rk.w] = s.w;
    } else {
        for (int e = base; e < E; ++e) csr[offs[dstv[e]] + rank[e]] = srcv[e];
    }
}

// ---------------- fused: deg-rank (returning atomics) || bf16 MFMA GEMM ----------------
template <int NC, int KK, int KREAL, bool AF32, bool DEG>
__global__ __launch_bounds__(512) void gemm_fused(
    const void* __restrict__ Ap, const short* __restrict__ Wcat,
    short* __restrict__ outL, short* __restrict__ outR, int M,
    const int* __restrict__ dstv, int* __restrict__ cnt, int* __restrict__ rank,
    int E, int degB)
{
    constexpr int BM = 128, BK = 64;
    constexpr int WN = NC / 4;
    constexpr int NJ = WN / 16;
    constexpr int CB = NC * 8 / 512;
    __shared__ __attribute__((aligned(16))) short sA[BM * BK];
    __shared__ __attribute__((aligned(16))) short sB[NC * BK];
    int tid = threadIdx.x;

    if (DEG && (int)blockIdx.x < degB) {
        int base = ((int)blockIdx.x * 512 + tid) * 4;
        if (base + 4 <= E) {
            int4 d = *(const int4*)(dstv + base);
            int4 rk;
            rk.x = atomicAdd(&cnt[d.x], 1);
            rk.y = atomicAdd(&cnt[d.y], 1);
            rk.z = atomicAdd(&cnt[d.z], 1);
            rk.w = atomicAdd(&cnt[d.w], 1);
            *(int4*)(rank + base) = rk;
        } else {
            for (int e = base; e < E; ++e) rank[e] = atomicAdd(&cnt[dstv[e]], 1);
        }
        return;
    }
    int bx = DEG ? ((int)blockIdx.x - degB) : (int)blockIdx.x;
    int wid = tid >> 6, lane = tid & 63;
    int wr = wid >> 2, wc = wid & 3;
    int row0 = bx * BM;
    bool full = (row0 + BM <= M);
    f32x4 acc[4][NJ] = {};
#pragma unroll
    for (int ksi = 0; ksi < KK / BK; ++ksi) {
        const int k0 = ksi * BK;
        // ---- stage A ----
        if (AF32) {
            const float* Af = (const float*)Ap;
#pragma unroll
            for (int it = 0; it < 2; ++it) {
                int i = it * 512 + tid;
                int r = i >> 3, oct = i & 7;
                int gr = row0 + r;
                int gk = k0 + oct * 8;
                bf16x8 v = {};
                if (gr < M) {
                    const float* p = Af + (size_t)gr * KREAL + gk;
                    if (k0 + BK <= KREAL) {   // compile-time after unroll
                        float2 f0 = *(const float2*)(p + 0);
                        float2 f1 = *(const float2*)(p + 2);
                        float2 f2 = *(const float2*)(p + 4);
                        float2 f3 = *(const float2*)(p + 6);
                        short2 p0 = f2x2(f0), p1 = f2x2(f1), p2 = f2x2(f2), p3 = f2x2(f3);
                        v[0] = p0.x; v[1] = p0.y; v[2] = p1.x; v[3] = p1.y;
                        v[4] = p2.x; v[5] = p2.y; v[6] = p3.x; v[7] = p3.y;
                    } else {
#pragma unroll
                        for (int j = 0; j < 4; ++j) {
                            if (gk + 2 * j + 2 <= KREAL) {
                                short2 pj = f2x2(*(const float2*)(p + 2 * j));
                                v[2 * j] = pj.x; v[2 * j + 1] = pj.y;
                            }
                        }
                    }
                }
                *(bf16x8*)((char*)sA + r * 128 + ((oct * 16) ^ ((r & 7) << 4))) = v;
            }
        } else {
            const char* Ab = (const char*)Ap;
            if (full) {
#pragma unroll
                for (int c = 0; c < 2; ++c) {
                    int idx = (wid * 2 + c) * 64 + lane;
                    int r = idx >> 3, cs = (idx & 7) * 16;
                    const char* g = Ab + (size_t)(row0 + r) * (KK * 2) + k0 * 2 + (cs ^ ((r & 7) << 4));
                    GLOAD16(g, (char*)sA + (size_t)(wid * 2 + c) * 1024);
                }
            } else {
                for (int t = tid; t < BM * 8; t += 512) {
                    int r = t >> 3, kc = (t & 7) * 16;
                    bf16x8 v = {};
                    int gr = row0 + r;
                    if (gr < M) v = *(const bf16x8*)(Ab + (size_t)gr * (KK * 2) + k0 * 2 + kc);
                    *(bf16x8*)((char*)sA + r * 128 + (kc ^ ((r & 7) << 4))) = v;
                }
            }
        }
        // ---- stage B: precomputed bf16 weights via global_load_lds ----
#pragma unroll
        for (int c = 0; c < CB; ++c) {
            int idx = (wid * CB + c) * 64 + lane;
            int r = idx >> 3, cs = (idx & 7) * 16;
            const char* g = (const char*)Wcat + (size_t)r * (KK * 2) + k0 * 2 + (cs ^ ((r & 7) << 4));
            GLOAD16(g, (char*)sB + (size_t)(wid * CB + c) * 1024);
        }
        __syncthreads();
        int rl = lane & 15;
        int sw = (rl & 7) << 4;
#pragma unroll
        for (int ks = 0; ks < 2; ++ks) {
            int kb2 = ks * 64 + (lane >> 4) * 16;
            int cswz = kb2 ^ sw;
            bf16x8 af[4];
#pragma unroll
            for (int mi = 0; mi < 4; ++mi) {
                int row = wr * 64 + mi * 16 + rl;
                af[mi] = *(const bf16x8*)((const char*)sA + row * 128 + cswz);
            }
#pragma unroll
            for (int ni = 0; ni < NJ; ++ni) {
                int rowb = wc * WN + ni * 16 + rl;
                bf16x8 bfr = *(const bf16x8*)((const char*)sB + rowb * 128 + cswz);
#pragma unroll
                for (int mi = 0; mi < 4; ++mi)
                    acc[mi][ni] = __builtin_amdgcn_mfma_f32_16x16x32_bf16(af[mi], bfr, acc[mi][ni], 0, 0, 0);
            }
        }
        __syncthreads();
    }
    constexpr int HN = NC / 2;
#pragma unroll
    for (int mi = 0; mi < 4; ++mi) {
#pragma unroll
        for (int ni = 0; ni < NJ; ++ni) {
            int gc = wc * WN + ni * 16 + (lane & 15);
#pragma unroll
            for (int r = 0; r < 4; ++r) {
                int gr = row0 + wr * 64 + mi * 16 + (lane >> 4) * 4 + r;
                if (gr < M) {
                    short v = f2b(acc[mi][ni][r]);
                    if (gc < HN) outL[(size_t)gr * HN + gc] = v;
                    else         outR[(size_t)gr * HN + gc - HN] = v;
                }
            }
        }
    }
}

// ------- fused mean-aggregate + residual + bias + relu (layer 1): 16 lanes/node ----
__global__ __launch_bounds__(256) void agg_fuse1(const int* __restrict__ offs,
                                                 const int* __restrict__ degs,
                                                 const int* __restrict__ csr,
                                                 const short* __restrict__ yl,
                                                 const short* __restrict__ yr,
                                                 const float* __restrict__ bias,
                                                 short* __restrict__ h, int Nn) {
    int gid = blockIdx.x * 16 + (threadIdx.x >> 4);
    int l = threadIdx.x & 15;
    if (gid >= Nn) return;
    int start = offs[gid], deg = degs[gid];
    const int co = l * 8;
    float a[8] = {};
    int t = 0;
    for (; t + 8 <= deg; t += 8) {
        int idx[8];
#pragma unroll
        for (int q = 0; q < 8; ++q) idx[q] = csr[start + t + q];
        bf16x8 vv[8];
#pragma unroll
        for (int q = 0; q < 8; ++q) vv[q] = *(const bf16x8*)(yl + (size_t)idx[q] * H1 + co);
#pragma unroll
        for (int j = 0; j < 8; ++j) {
            float s = 0.f;
#pragma unroll
            for (int q = 0; q < 8; ++q) s += b2f(vv[q][j]);
            a[j] += s;
        }
    }
    for (; t + 4 <= deg; t += 4) {
        int i0 = csr[start + t], i1 = csr[start + t + 1];
        int i2 = csr[start + t + 2], i3 = csr[start + t + 3];
        bf16x8 v0 = *(const bf16x8*)(yl + (size_t)i0 * H1 + co);
        bf16x8 v1 = *(const bf16x8*)(yl + (size_t)i1 * H1 + co);
        bf16x8 v2 = *(const bf16x8*)(yl + (size_t)i2 * H1 + co);
        bf16x8 v3 = *(const bf16x8*)(yl + (size_t)i3 * H1 + co);
#pragma unroll
        for (int j = 0; j < 8; ++j)
            a[j] += b2f(v0[j]) + b2f(v1[j]) + b2f(v2[j]) + b2f(v3[j]);
    }
    for (; t < deg; ++t) {
        int s = csr[start + t];
        bf16x8 v = *(const bf16x8*)(yl + (size_t)s * H1 + co);
#pragma unroll
        for (int j = 0; j < 8; ++j) a[j] += b2f(v[j]);
    }
    float inv = 1.f / fmaxf((float)deg, 1.f);
    bf16x8 rv = *(const bf16x8*)(yr + (size_t)gid * H1 + co);
    bf16x8 o;
#pragma unroll
    for (int j = 0; j < 4; ++j) {
        float r0 = fmaxf(a[2 * j] * inv + b2f(rv[2 * j]) + bias[co + 2 * j], 0.f);
        float r1 = fmaxf(a[2 * j + 1] * inv + b2f(rv[2 * j + 1]) + bias[co + 2 * j + 1], 0.f);
        o[2 * j] = f2b(r0); o[2 * j + 1] = f2b(r1);
    }
    *(bf16x8*)(h + (size_t)gid * H1 + co) = o;
}

// ------- fused agg + residual + bias + relu + head + log_softmax (layer 2): 16 lanes/node ----
__global__ __launch_bounds__(256) void agg_head2(const int* __restrict__ offs,
                                                 const int* __restrict__ degs,
                                                 const int* __restrict__ csr,
                                                 const short* __restrict__ yl,
                                                 const short* __restrict__ yr,
                                                 const float* __restrict__ bias,
                                                 const float* __restrict__ Wlin,
                                                 const float* __restrict__ blin,
                                                 float* __restrict__ out, int Nn) {
    int gid = blockIdx.x * 16 + (threadIdx.x >> 4);
    int l = threadIdx.x & 15;
    if (gid >= Nn) return;
    int start = offs[gid], deg = degs[gid];
    const int co = l * 4;
    float a[4] = {};
    int t = 0;
    for (; t + 8 <= deg; t += 8) {
        int idx[8];
#pragma unroll
        for (int q = 0; q < 8; ++q) idx[q] = csr[start + t + q];
        short4 vv[8];
#pragma unroll
        for (int q = 0; q < 8; ++q) vv[q] = *(const short4*)(yl + (size_t)idx[q] * H2 + co);
#pragma unroll
        for (int q = 0; q < 8; ++q) {
            a[0] += b2f(vv[q].x); a[1] += b2f(vv[q].y);
            a[2] += b2f(vv[q].z); a[3] += b2f(vv[q].w);
        }
    }
    for (; t + 4 <= deg; t += 4) {
        int i0 = csr[start + t], i1 = csr[start + t + 1];
        int i2 = csr[start + t + 2], i3 = csr[start + t + 3];
        short4 v0 = *(const short4*)(yl + (size_t)i0 * H2 + co);
        short4 v1 = *(const short4*)(yl + (size_t)i1 * H2 + co);
        short4 v2 = *(const short4*)(yl + (size_t)i2 * H2 + co);
        short4 v3 = *(const short4*)(yl + (size_t)i3 * H2 + co);
        a[0] += b2f(v0.x) + b2f(v1.x) + b2f(v2.x) + b2f(v3.x);
        a[1] += b2f(v0.y) + b2f(v1.y) + b2f(v2.y) + b2f(v3.y);
        a[2] += b2f(v0.z) + b2f(v1.z) + b2f(v2.z) + b2f(v3.z);
        a[3] += b2f(v0.w) + b2f(v1.w) + b2f(v2.w) + b2f(v3.w);
    }
    for (; t < deg; ++t) {
        int s = csr[start + t];
        short4 v = *(const short4*)(yl + (size_t)s * H2 + co);
        a[0] += b2f(v.x); a[1] += b2f(v.y); a[2] += b2f(v.z); a[3] += b2f(v.w);
    }
    float inv = 1.f / fmaxf((float)deg, 1.f);
    short4 rv = *(const short4*)(yr + (size_t)gid * H2 + co);
    float h0 = fmaxf(a[0] * inv + b2f(rv.x) + bias[co + 0], 0.f);
    float h1v = fmaxf(a[1] * inv + b2f(rv.y) + bias[co + 1], 0.f);
    float h2v = fmaxf(a[2] * inv + b2f(rv.z) + bias[co + 2], 0.f);
    float h3v = fmaxf(a[3] * inv + b2f(rv.w) + bias[co + 3], 0.f);
    float g0 = h0 * Wlin[co] + h1v * Wlin[co + 1] + h2v * Wlin[co + 2] + h3v * Wlin[co + 3];
    float g1 = h0 * Wlin[64 + co] + h1v * Wlin[64 + co + 1] + h2v * Wlin[64 + co + 2] + h3v * Wlin[64 + co + 3];
#pragma unroll
    for (int m = 8; m >= 1; m >>= 1) {
        g0 += __shfl_xor(g0, m, 16);
        g1 += __shfl_xor(g1, m, 16);
    }
    if (l == 0) {
        g0 += blin[0]; g1 += blin[1];
        float mx = fmaxf(g0, g1);
        float lse = mx + logf(expf(g0 - mx) + expf(g1 - mx));
        float2 r; r.x = g0 - lse; r.y = g1 - lse;
        ((float2*)out)[gid] = r;
    }
}

extern "C" void kernel_launch(void* const* d_in, const int* in_sizes, int n_in,
                              void* d_out, int out_size, void* d_ws, size_t ws_size,
                              hipStream_t stream) {
    const float* x    = (const float*)d_in[0];
    const int*   ei   = (const int*)d_in[1];
    const float* W1l  = (const float*)d_in[2];
    const float* W1r  = (const float*)d_in[3];
    const float* b1   = (const float*)d_in[4];
    const float* W2l  = (const float*)d_in[5];
    const float* W2r  = (const float*)d_in[6];
    const float* b2   = (const float*)d_in[7];
    const float* Wlin = (const float*)d_in[8];
    const float* blin = (const float*)d_in[9];
    float* outp = (float*)d_out;

    const int N = in_sizes[0] / F_IN;
    const int E = in_sizes[1] / 2;
    const int* srcv = ei;
    const int* dstv = ei + E;

    char* ws = (char*)d_ws;
    size_t o = 0;
    auto alloc = [&](size_t bytes) { size_t r = o; o += (bytes + 255) & ~(size_t)255; return r; };
    int* cnt_i  = (int*)(ws + alloc((size_t)N * 4));
    int* offs   = (int*)(ws + alloc((size_t)N * 4));
    int* bsums  = (int*)(ws + alloc(1024));
    int* rank   = (int*)(ws + alloc((size_t)E * 4));
    int* csr    = (int*)(ws + alloc((size_t)E * 4));
    short* wc1  = (short*)(ws + alloc((size_t)256 * 192 * 2));
    short* wc2  = (short*)(ws + alloc((size_t)128 * 128 * 2));
    short* y1l  = (short*)(ws + alloc((size_t)N * H1 * 2));
    short* y1r  = (short*)(ws + alloc((size_t)N * H1 * 2));
    short* h1   = (short*)(ws + alloc((size_t)N * H1 * 2));
    short* y2l  = y1l;
    short* y2r  = y1r;

    const int zB   = (N + 1023) / 1024;
    const int degB = (E + 2047) / 2048;
    const int nb   = (N + 2047) / 2048;
    const int nthr = (N + 255) / 256;
    const int gblk = (N + 127) / 128;
    const int e4   = (E + 1023) / 1024;
    const int a16  = (N + 15) / 16;

    prelude<<<zB + 192 + 64, 256, 0, stream>>>(cnt_i, N, zB, W1l, W1r, wc1, W2l, W2r, wc2);

    // K1: deg-rank (returning atomics) || GEMM1 from fp32 x and bf16 wc1
    gemm_fused<256, 192, F_IN, true, true><<<degB + gblk, 512, 0, stream>>>(
        x, wc1, y1l, y1r, N, dstv, cnt_i, rank, E, degB);

    scan_block<<<nb, 256, 0, stream>>>(cnt_i, offs, bsums, N);
    scan_add<<<nthr, 256, 0, stream>>>(offs, bsums, nb, N);

    csr_scatter<<<e4, 256, 0, stream>>>(srcv, dstv, rank, offs, csr, E);

    agg_fuse1<<<a16, 256, 0, stream>>>(offs, cnt_i, csr, y1l, y1r, b1, h1, N);

    gemm_fused<128, 128, 128, false, false><<<gblk, 512, 0, stream>>>(
        h1, wc2, y2l, y2r, N, nullptr, nullptr, nullptr, 0, 0);

    agg_head2<<<a16, 256, 0, stream>>>(offs, cnt_i, csr, y2l, y2r, b2, Wlin, blin, outp, N);
}

// Round 11
// 168.581 us; speedup vs baseline: 4.8339x; 1.0061x over previous
//
#include <hip/hip_runtime.h>
#include <hip/hip_bf16.h>
#include <math.h>

#define F_IN 182
#define H1   128
#define H2   64

typedef short bf16x8 __attribute__((ext_vector_type(8)));
typedef float f32x4 __attribute__((ext_vector_type(4)));

__device__ __forceinline__ float b2f(short s) {
    unsigned u = ((unsigned)(unsigned short)s) << 16;
    return __builtin_bit_cast(float, u);
}
__device__ __forceinline__ short f2b(float f) {
    return __builtin_bit_cast(short, __float2bfloat16(f));
}
__device__ __forceinline__ short2 f2x2(float2 f) {
    short2 r;
    r.x = f2b(f.x);
    r.y = f2b(f.y);
    return r;
}

#define GLOAD16(g, l) __builtin_amdgcn_global_load_lds( \
    (const __attribute__((address_space(1))) void*)(g), \
    (__attribute__((address_space(3))) void*)(l), 16, 0, 0)

// ---------------- prelude: zero cnt || conv W1 -> bf16 [256][192] || W2 -> bf16 [128][128] ----
__global__ __launch_bounds__(256) void prelude(
    int* __restrict__ cnt, int Nn, int zB,
    const float* __restrict__ W1l, const float* __restrict__ W1r, short* __restrict__ wc1,
    const float* __restrict__ W2l, const float* __restrict__ W2r, short* __restrict__ wc2)
{
    int b = blockIdx.x, tid = threadIdx.x;
    if (b < zB) {
        int i = (b * 256 + tid) * 4;
        if (i + 4 <= Nn) {
            int4 z = make_int4(0, 0, 0, 0);
            *(int4*)(cnt + i) = z;
        } else {
            for (int j = i; j < Nn; ++j) cnt[j] = 0;
        }
        return;
    }
    b -= zB;
    if (b < 192) {
        int idx = b * 256 + tid;
        int r = idx / 192, k = idx - r * 192;
        float v = 0.f;
        if (k < F_IN) v = (r < 128) ? W1l[r * F_IN + k] : W1r[(r - 128) * F_IN + k];
        wc1[idx] = f2b(v);
        return;
    }
    b -= 192;
    {
        int idx = b * 256 + tid;
        int r = idx >> 7, k = idx & 127;
        float v = (r < 64) ? W2l[r * 128 + k] : W2r[(r - 64) * 128 + k];
        wc2[idx] = f2b(v);
    }
}

// ---------------- scans ----------------
__global__ __launch_bounds__(256) void scan_block(const int* __restrict__ in,
                                                  int* __restrict__ out,
                                                  int* __restrict__ bsums, int Nn) {
    __shared__ int s[256];
    int b = blockIdx.x, t = threadIdx.x;
    int base = b * 2048 + t * 8;
    int v[8]; int sum = 0;
#pragma unroll
    for (int i = 0; i < 8; ++i) { int idx = base + i; v[i] = (idx < Nn) ? in[idx] : 0; sum += v[i]; }
    s[t] = sum; __syncthreads();
    for (int off = 1; off < 256; off <<= 1) {
        int x = (t >= off) ? s[t - off] : 0; __syncthreads();
        s[t] += x; __syncthreads();
    }
    int excl = s[t] - sum;
    if (t == 255) bsums[b] = s[255];
    int run = excl;
#pragma unroll
    for (int i = 0; i < 8; ++i) { int idx = base + i; if (idx < Nn) out[idx] = run; run += v[i]; }
}

// scan_add with inlined bsums exclusive scan (nb <= 64)
__global__ __launch_bounds__(256) void scan_add(int* __restrict__ offs,
                                                const int* __restrict__ bsums,
                                                int nb, int Nn) {
    __shared__ int sbs[64];
    int t = threadIdx.x;
    if (t < 64) {
        int v = (t < nb) ? bsums[t] : 0;
        int s = v;
#pragma unroll
        for (int off = 1; off < 64; off <<= 1) {
            int u = __shfl_up(s, off, 64);
            if (t >= off) s += u;
        }
        sbs[t] = s - v;
    }
    __syncthreads();
    int i = blockIdx.x * 256 + t;
    if (i < Nn) offs[i] += sbs[i >> 11];
}

// ---------------- atomic-free CSR fill using precomputed ranks (8 edges/thread) ----------------
__global__ __launch_bounds__(256) void csr_scatter(const int* __restrict__ srcv,
                                                   const int* __restrict__ dstv,
                                                   const int* __restrict__ rank,
                                                   const int* __restrict__ offs,
                                                   int* __restrict__ csr, int E) {
    int base = (blockIdx.x * 256 + threadIdx.x) * 8;
    if (base + 8 <= E) {
        int4 d0 = *(const int4*)(dstv + base);
        int4 d1 = *(const int4*)(dstv + base + 4);
        int4 s0 = *(const int4*)(srcv + base);
        int4 s1 = *(const int4*)(srcv + base + 4);
        int4 r0 = *(const int4*)(rank + base);
        int4 r1 = *(const int4*)(rank + base + 4);
        csr[offs[d0.x] + r0.x] = s0.x;
        csr[offs[d0.y] + r0.y] = s0.y;
        csr[offs[d0.z] + r0.z] = s0.z;
        csr[offs[d0.w] + r0.w] = s0.w;
        csr[offs[d1.x] + r1.x] = s1.x;
        csr[offs[d1.y] + r1.y] = s1.y;
        csr[offs[d1.z] + r1.z] = s1.z;
        csr[offs[d1.w] + r1.w] = s1.w;
    } else {
        for (int e = base; e < E; ++e) csr[offs[dstv[e]] + rank[e]] = srcv[e];
    }
}

// ---------------- fused: deg-rank (returning atomics) || GEMM1 (fp32 x -> bf16 in staging) ----
template <int NC, int KK, int KREAL, bool DEG>
__global__ __launch_bounds__(512) void gemm_fused(
    const void* __restrict__ Ap, const short* __restrict__ Wcat,
    short* __restrict__ outL, short* __restrict__ outR, int M,
    const int* __restrict__ dstv, int* __restrict__ cnt, int* __restrict__ rank,
    int E, int degB)
{
    constexpr int BM = 128, BK = 64;
    constexpr int WN = NC / 4;
    constexpr int NJ = WN / 16;
    constexpr int CB = NC * 8 / 512;
    __shared__ __attribute__((aligned(16))) short sA[BM * BK];
    __shared__ __attribute__((aligned(16))) short sB[NC * BK];
    int tid = threadIdx.x;

    if (DEG && (int)blockIdx.x < degB) {
        int base = ((int)blockIdx.x * 512 + tid) * 4;
        if (base + 4 <= E) {
            int4 d = *(const int4*)(dstv + base);
            int4 rk;
            rk.x = atomicAdd(&cnt[d.x], 1);
            rk.y = atomicAdd(&cnt[d.y], 1);
            rk.z = atomicAdd(&cnt[d.z], 1);
            rk.w = atomicAdd(&cnt[d.w], 1);
            *(int4*)(rank + base) = rk;
        } else {
            for (int e = base; e < E; ++e) rank[e] = atomicAdd(&cnt[dstv[e]], 1);
        }
        return;
    }
    int bx = DEG ? ((int)blockIdx.x - degB) : (int)blockIdx.x;
    int wid = tid >> 6, lane = tid & 63;
    int wr = wid >> 2, wc = wid & 3;
    int row0 = bx * BM;
    f32x4 acc[4][NJ] = {};
#pragma unroll
    for (int ksi = 0; ksi < KK / BK; ++ksi) {
        const int k0 = ksi * BK;
        // ---- stage A: fp32 -> bf16 ----
        {
            const float* Af = (const float*)Ap;
#pragma unroll
            for (int it = 0; it < 2; ++it) {
                int i = it * 512 + tid;
                int r = i >> 3, oct = i & 7;
                int gr = row0 + r;
                int gk = k0 + oct * 8;
                bf16x8 v = {};
                if (gr < M) {
                    const float* p = Af + (size_t)gr * KREAL + gk;
                    if (k0 + BK <= KREAL) {
                        float2 f0 = *(const float2*)(p + 0);
                        float2 f1 = *(const float2*)(p + 2);
                        float2 f2 = *(const float2*)(p + 4);
                        float2 f3 = *(const float2*)(p + 6);
                        short2 p0 = f2x2(f0), p1 = f2x2(f1), p2 = f2x2(f2), p3 = f2x2(f3);
                        v[0] = p0.x; v[1] = p0.y; v[2] = p1.x; v[3] = p1.y;
                        v[4] = p2.x; v[5] = p2.y; v[6] = p3.x; v[7] = p3.y;
                    } else {
#pragma unroll
                        for (int j = 0; j < 4; ++j) {
                            if (gk + 2 * j + 2 <= KREAL) {
                                short2 pj = f2x2(*(const float2*)(p + 2 * j));
                                v[2 * j] = pj.x; v[2 * j + 1] = pj.y;
                            }
                        }
                    }
                }
                *(bf16x8*)((char*)sA + r * 128 + ((oct * 16) ^ ((r & 7) << 4))) = v;
            }
        }
        // ---- stage B: precomputed bf16 weights via global_load_lds ----
#pragma unroll
        for (int c = 0; c < CB; ++c) {
            int idx = (wid * CB + c) * 64 + lane;
            int r = idx >> 3, cs = (idx & 7) * 16;
            const char* g = (const char*)Wcat + (size_t)r * (KK * 2) + k0 * 2 + (cs ^ ((r & 7) << 4));
            GLOAD16(g, (char*)sB + (size_t)(wid * CB + c) * 1024);
        }
        __syncthreads();
        int rl = lane & 15;
        int sw = (rl & 7) << 4;
#pragma unroll
        for (int ks = 0; ks < 2; ++ks) {
            int kb2 = ks * 64 + (lane >> 4) * 16;
            int cswz = kb2 ^ sw;
            bf16x8 af[4];
#pragma unroll
            for (int mi = 0; mi < 4; ++mi) {
                int row = wr * 64 + mi * 16 + rl;
                af[mi] = *(const bf16x8*)((const char*)sA + row * 128 + cswz);
            }
#pragma unroll
            for (int ni = 0; ni < NJ; ++ni) {
                int rowb = wc * WN + ni * 16 + rl;
                bf16x8 bfr = *(const bf16x8*)((const char*)sB + rowb * 128 + cswz);
#pragma unroll
                for (int mi = 0; mi < 4; ++mi)
                    acc[mi][ni] = __builtin_amdgcn_mfma_f32_16x16x32_bf16(af[mi], bfr, acc[mi][ni], 0, 0, 0);
            }
        }
        __syncthreads();
    }
    constexpr int HN = NC / 2;
#pragma unroll
    for (int mi = 0; mi < 4; ++mi) {
#pragma unroll
        for (int ni = 0; ni < NJ; ++ni) {
            int gc = wc * WN + ni * 16 + (lane & 15);
#pragma unroll
            for (int r = 0; r < 4; ++r) {
                int gr = row0 + wr * 64 + mi * 16 + (lane >> 4) * 4 + r;
                if (gr < M) {
                    short v = f2b(acc[mi][ni][r]);
                    if (gc < HN) outL[(size_t)gr * HN + gc] = v;
                    else         outR[(size_t)gr * HN + gc - HN] = v;
                }
            }
        }
    }
}

// ------- fused layer-1 aggregation + GEMM2: build h1 tile in LDS, then y2 = h1 @ W2cat^T ----
// sA: [128][128] bf16 (full K), built by aggregation. sB: full wc2 [128][128] via gload16.
__global__ __launch_bounds__(512) void agg_gemm2(
    const int* __restrict__ offs, const int* __restrict__ degs, const int* __restrict__ csr,
    const short* __restrict__ y1l, const short* __restrict__ y1r,
    const float* __restrict__ b1, const short* __restrict__ wc2,
    short* __restrict__ outL, short* __restrict__ outR, int M)
{
    constexpr int BM = 128, KK = 128, NC = 128;
    constexpr int WN = NC / 4;   // 32
    constexpr int NJ = WN / 16;  // 2
    __shared__ __attribute__((aligned(16))) short sA[BM * KK];  // 32 KB, rows of 256 B, swizzled
    __shared__ __attribute__((aligned(16))) short sB[NC * KK];  // 32 KB
    int tid = threadIdx.x;
    int wid = tid >> 6, lane = tid & 63;
    int wr = wid >> 2, wc = wid & 3;
    int row0 = (int)blockIdx.x * BM;

    // ---- issue B staging first (async, drains at the barrier) ----
#pragma unroll
    for (int it = 0; it < 4; ++it) {
        int idx = (wid * 4 + it) * 64 + lane;          // 0..2047
        int r = idx >> 4, c16 = (idx & 15) * 16;       // row, byte col
        const char* g = (const char*)wc2 + (size_t)r * 256 + (c16 ^ ((r & 7) << 4));
        GLOAD16(g, (char*)sB + (size_t)(wid * 4 + it) * 1024);
    }

    // ---- aggregation phase: 32 rows at a time (16 lanes x 8 bf16 per row) ----
    int rlocal = tid >> 4;       // 0..31
    int l = tid & 15;
    const int co = l * 8;
#pragma unroll
    for (int rr = 0; rr < 4; ++rr) {
        int r = rr * 32 + rlocal;
        int gid = row0 + r;
        bf16x8 o = {};
        if (gid < M) {
            int start = offs[gid], deg = degs[gid];
            float a[8] = {};
            int t = 0;
            for (; t + 8 <= deg; t += 8) {
                int idx[8];
#pragma unroll
                for (int q = 0; q < 8; ++q) idx[q] = csr[start + t + q];
                bf16x8 vv[8];
#pragma unroll
                for (int q = 0; q < 8; ++q) vv[q] = *(const bf16x8*)(y1l + (size_t)idx[q] * H1 + co);
#pragma unroll
                for (int j = 0; j < 8; ++j) {
                    float s = 0.f;
#pragma unroll
                    for (int q = 0; q < 8; ++q) s += b2f(vv[q][j]);
                    a[j] += s;
                }
            }
            for (; t + 4 <= deg; t += 4) {
                int i0 = csr[start + t], i1 = csr[start + t + 1];
                int i2 = csr[start + t + 2], i3 = csr[start + t + 3];
                bf16x8 v0 = *(const bf16x8*)(y1l + (size_t)i0 * H1 + co);
                bf16x8 v1 = *(const bf16x8*)(y1l + (size_t)i1 * H1 + co);
                bf16x8 v2 = *(const bf16x8*)(y1l + (size_t)i2 * H1 + co);
                bf16x8 v3 = *(const bf16x8*)(y1l + (size_t)i3 * H1 + co);
#pragma unroll
                for (int j = 0; j < 8; ++j)
                    a[j] += b2f(v0[j]) + b2f(v1[j]) + b2f(v2[j]) + b2f(v3[j]);
            }
            for (; t < deg; ++t) {
                int s = csr[start + t];
                bf16x8 v = *(const bf16x8*)(y1l + (size_t)s * H1 + co);
#pragma unroll
                for (int j = 0; j < 8; ++j) a[j] += b2f(v[j]);
            }
            float inv = 1.f / fmaxf((float)deg, 1.f);
            bf16x8 rv = *(const bf16x8*)(y1r + (size_t)gid * H1 + co);
#pragma unroll
            for (int j = 0; j < 8; ++j)
                o[j] = f2b(fmaxf(a[j] * inv + b2f(rv[j]) + b1[co + j], 0.f));
        }
        *(bf16x8*)((char*)sA + r * 256 + ((co * 2) ^ ((r & 7) << 4))) = o;
    }
    __syncthreads();   // waits LDS writes and drains gload16s

    // ---- GEMM: y2 = sA @ sB^T (both full-K in LDS; no further barriers) ----
    f32x4 acc[4][NJ] = {};
    int rl = lane & 15;
    int sw = (rl & 7) << 4;
#pragma unroll
    for (int ks = 0; ks < 8; ++ks) {       // 8 x 16-byte K-slices (K=128)
        int kb2 = ks * 16 + 0;
        // order: interleave slice selection across lane>>4 groups like gemm_fused
        int kcol = ((ks & 3) * 4 + (lane >> 4)) * 16;  // byte col 0..240
        (void)kb2;
        if (ks < 4) kcol = (ks * 4 + (lane >> 4)) * 16;
        else        kcol = ((ks - 4) * 4 + (lane >> 4)) * 16;
        // two passes over the same 4 slices would double-count; use ks 0..3 only
        if (ks >= 4) break;
        int cswz = kcol ^ sw;
        bf16x8 af[4];
#pragma unroll
        for (int mi = 0; mi < 4; ++mi) {
            int row = wr * 64 + mi * 16 + rl;
            af[mi] = *(const bf16x8*)((const char*)sA + row * 256 + cswz);
        }
#pragma unroll
        for (int ni = 0; ni < NJ; ++ni) {
            int rowb = wc * WN + ni * 16 + rl;
            bf16x8 bfr = *(const bf16x8*)((const char*)sB + rowb * 256 + cswz);
#pragma unroll
            for (int mi = 0; mi < 4; ++mi)
                acc[mi][ni] = __builtin_amdgcn_mfma_f32_16x16x32_bf16(af[mi], bfr, acc[mi][ni], 0, 0, 0);
        }
    }
    constexpr int HN = NC / 2;
#pragma unroll
    for (int mi = 0; mi < 4; ++mi) {
#pragma unroll
        for (int ni = 0; ni < NJ; ++ni) {
            int gc = wc * WN + ni * 16 + (lane & 15);
#pragma unroll
            for (int r = 0; r < 4; ++r) {
                int gr = row0 + wr * 64 + mi * 16 + (lane >> 4) * 4 + r;
                if (gr < M) {
                    short v = f2b(acc[mi][ni][r]);
                    if (gc < HN) outL[(size_t)gr * HN + gc] = v;
                    else         outR[(size_t)gr * HN + gc - HN] = v;
                }
            }
        }
    }
}

// ------- fused agg + residual + bias + relu + head + log_softmax (layer 2): 16 lanes/node ----
__global__ __launch_bounds__(256) void agg_head2(const int* __restrict__ offs,
                                                 const int* __restrict__ degs,
                                                 const int* __restrict__ csr,
                                                 const short* __restrict__ yl,
                                                 const short* __restrict__ yr,
                                                 const float* __restrict__ bias,
                                                 const float* __restrict__ Wlin,
                                                 const float* __restrict__ blin,
                                                 float* __restrict__ out, int Nn) {
    int gid = blockIdx.x * 16 + (threadIdx.x >> 4);
    int l = threadIdx.x & 15;
    if (gid >= Nn) return;
    int start = offs[gid], deg = degs[gid];
    const int co = l * 4;
    float a[4] = {};
    int t = 0;
    for (; t + 8 <= deg; t += 8) {
        int idx[8];
#pragma unroll
        for (int q = 0; q < 8; ++q) idx[q] = csr[start + t + q];
        short4 vv[8];
#pragma unroll
        for (int q = 0; q < 8; ++q) vv[q] = *(const short4*)(yl + (size_t)idx[q] * H2 + co);
#pragma unroll
        for (int q = 0; q < 8; ++q) {
            a[0] += b2f(vv[q].x); a[1] += b2f(vv[q].y);
            a[2] += b2f(vv[q].z); a[3] += b2f(vv[q].w);
        }
    }
    for (; t + 4 <= deg; t += 4) {
        int i0 = csr[start + t], i1 = csr[start + t + 1];
        int i2 = csr[start + t + 2], i3 = csr[start + t + 3];
        short4 v0 = *(const short4*)(yl + (size_t)i0 * H2 + co);
        short4 v1 = *(const short4*)(yl + (size_t)i1 * H2 + co);
        short4 v2 = *(const short4*)(yl + (size_t)i2 * H2 + co);
        short4 v3 = *(const short4*)(yl + (size_t)i3 * H2 + co);
        a[0] += b2f(v0.x) + b2f(v1.x) + b2f(v2.x) + b2f(v3.x);
        a[1] += b2f(v0.y) + b2f(v1.y) + b2f(v2.y) + b2f(v3.y);
        a[2] += b2f(v0.z) + b2f(v1.z) + b2f(v2.z) + b2f(v3.z);
        a[3] += b2f(v0.w) + b2f(v1.w) + b2f(v2.w) + b2f(v3.w);
    }
    for (; t < deg; ++t) {
        int s = csr[start + t];
        short4 v = *(const short4*)(yl + (size_t)s * H2 + co);
        a[0] += b2f(v.x); a[1] += b2f(v.y); a[2] += b2f(v.z); a[3] += b2f(v.w);
    }
    float inv = 1.f / fmaxf((float)deg, 1.f);
    short4 rv = *(const short4*)(yr + (size_t)gid * H2 + co);
    float h0 = fmaxf(a[0] * inv + b2f(rv.x) + bias[co + 0], 0.f);
    float h1v = fmaxf(a[1] * inv + b2f(rv.y) + bias[co + 1], 0.f);
    float h2v = fmaxf(a[2] * inv + b2f(rv.z) + bias[co + 2], 0.f);
    float h3v = fmaxf(a[3] * inv + b2f(rv.w) + bias[co + 3], 0.f);
    float g0 = h0 * Wlin[co] + h1v * Wlin[co + 1] + h2v * Wlin[co + 2] + h3v * Wlin[co + 3];
    float g1 = h0 * Wlin[64 + co] + h1v * Wlin[64 + co + 1] + h2v * Wlin[64 + co + 2] + h3v * Wlin[64 + co + 3];
#pragma unroll
    for (int m = 8; m >= 1; m >>= 1) {
        g0 += __shfl_xor(g0, m, 16);
        g1 += __shfl_xor(g1, m, 16);
    }
    if (l == 0) {
        g0 += blin[0]; g1 += blin[1];
        float mx = fmaxf(g0, g1);
        float lse = mx + logf(expf(g0 - mx) + expf(g1 - mx));
        float2 r; r.x = g0 - lse; r.y = g1 - lse;
        ((float2*)out)[gid] = r;
    }
}

extern "C" void kernel_launch(void* const* d_in, const int* in_sizes, int n_in,
                              void* d_out, int out_size, void* d_ws, size_t ws_size,
                              hipStream_t stream) {
    const float* x    = (const float*)d_in[0];
    const int*   ei   = (const int*)d_in[1];
    const float* W1l  = (const float*)d_in[2];
    const float* W1r  = (const float*)d_in[3];
    const float* b1   = (const float*)d_in[4];
    const float* W2l  = (const float*)d_in[5];
    const float* W2r  = (const float*)d_in[6];
    const float* b2   = (const float*)d_in[7];
    const float* Wlin = (const float*)d_in[8];
    const float* blin = (const float*)d_in[9];
    float* outp = (float*)d_out;

    const int N = in_sizes[0] / F_IN;
    const int E = in_sizes[1] / 2;
    const int* srcv = ei;
    const int* dstv = ei + E;

    char* ws = (char*)d_ws;
    size_t o = 0;
    auto alloc = [&](size_t bytes) { size_t r = o; o += (bytes + 255) & ~(size_t)255; return r; };
    int* cnt_i  = (int*)(ws + alloc((size_t)N * 4));
    int* offs   = (int*)(ws + alloc((size_t)N * 4));
    int* bsums  = (int*)(ws + alloc(1024));
    int* rank   = (int*)(ws + alloc((size_t)E * 4));
    int* csr    = (int*)(ws + alloc((size_t)E * 4));
    short* wc1  = (short*)(ws + alloc((size_t)256 * 192 * 2));
    short* wc2  = (short*)(ws + alloc((size_t)128 * 128 * 2));
    short* y1l  = (short*)(ws + alloc((size_t)N * H1 * 2));
    short* y1r  = (short*)(ws + alloc((size_t)N * H1 * 2));
    short* y2l  = (short*)(ws + alloc((size_t)N * H2 * 2));
    short* y2r  = (short*)(ws + alloc((size_t)N * H2 * 2));

    const int zB   = (N + 1023) / 1024;
    const int degB = (E + 2047) / 2048;
    const int nb   = (N + 2047) / 2048;
    const int nthr = (N + 255) / 256;
    const int gblk = (N + 127) / 128;
    const int e8   = (E + 2047) / 2048;
    const int a16  = (N + 15) / 16;

    prelude<<<zB + 192 + 64, 256, 0, stream>>>(cnt_i, N, zB, W1l, W1r, wc1, W2l, W2r, wc2);

    // K1: deg-rank (returning atomics) || GEMM1 from fp32 x and bf16 wc1
    gemm_fused<256, 192, F_IN, true><<<degB + gblk, 512, 0, stream>>>(
        x, wc1, y1l, y1r, N, dstv, cnt_i, rank, E, degB);

    scan_block<<<nb, 256, 0, stream>>>(cnt_i, offs, bsums, N);
    scan_add<<<nthr, 256, 0, stream>>>(offs, bsums, nb, N);

    csr_scatter<<<e8, 256, 0, stream>>>(srcv, dstv, rank, offs, csr, E);

    // fused layer-1 aggregation + GEMM2 (h1 never hits global memory)
    agg_gemm2<<<gblk, 512, 0, stream>>>(offs, cnt_i, csr, y1l, y1r, b1, wc2, y2l, y2r, N);

    agg_head2<<<a16, 256, 0, stream>>>(offs, cnt_i, csr, y2l, y2r, b2, Wlin, blin, outp, N);
}